// Round 12
// baseline (12642.529 us; speedup 1.0000x reference)
//
#include <hip/hip_runtime.h>
#include <stdint.h>
#include <stddef.h>

#define TT   128
#define GATE 4128
#define VOC  32000
#define NWG  256

typedef float  f32x4 __attribute__((ext_vector_type(4)));
typedef short  bf16x8 __attribute__((ext_vector_type(8)));
typedef unsigned short u16x4 __attribute__((ext_vector_type(4)));

__device__ __forceinline__ float bf2f(ushort u){
  union { uint32_t i; float f; } c; c.i = ((uint32_t)u) << 16; return c.f;
}
__device__ __forceinline__ ushort f2bf(float x){
  uint32_t u = __builtin_bit_cast(uint32_t, x);
  uint32_t r = (u + 0x7fffu + ((u >> 16) & 1u)) >> 16;
  return (ushort)r;
}

// ---------------------------------------------------------------- embed
__global__ void embed_kernel(const int* __restrict__ ys, const float* __restrict__ emb,
                             float* __restrict__ x){
  int r = blockIdx.x;
  int t = r >> 3, b = r & 7;
  int tok = ys[b*129 + t];
  f32x4 v = *(const f32x4*)&emb[(size_t)tok*512 + threadIdx.x*4];
  *(f32x4*)&x[(size_t)r*512 + threadIdx.x*4] = v;
}

// ---------------------------------------------------------------- full Wh transpose
__global__ void whT_kernel(const float* __restrict__ Wh, float* __restrict__ WhT){
  __shared__ float tile[32][33];
  int g0 = blockIdx.x*32, k0 = blockIdx.y*32;
  int tx = threadIdx.x, ty = threadIdx.y;
  for (int i = ty; i < 32; i += 8)
    tile[i][tx] = Wh[(size_t)(k0+i)*GATE + g0 + tx];
  __syncthreads();
  for (int i = ty; i < 32; i += 8)
    WhT[(size_t)(g0+i)*1024 + k0 + tx] = tile[tx][i];
}

// ---------------------------------------------------------------- WhmT[k][c]
__global__ void whmT_kernel(const float* __restrict__ Wh, float* __restrict__ WhmT){
  int idx = blockIdx.x*256 + threadIdx.x;
  int k = idx >> 5, c = idx & 31;
  WhmT[idx] = Wh[(size_t)k*GATE + 4096 + c];
}

// ---------------------------------------------------------------- Wo -> pre-swizzled split-bf16 tile images
__global__ __launch_bounds__(256) void wosplit_kernel(const float* __restrict__ Wo,
                                                      uint32_t* __restrict__ hi_img,
                                                      uint32_t* __restrict__ lo_img){
  __shared__ float tile[32][132];
  int ks = blockIdx.x, nt = blockIdx.y;
  int tid = threadIdx.x;
  for (int i = tid; i < 4096; i += 256)
    tile[i>>7][i&127] = Wo[(size_t)(ks*32 + (i>>7))*VOC + nt*128 + (i&127)];
  __syncthreads();
  size_t base = ((size_t)(nt*32 + ks)) << 11;
  for (int i = tid; i < 2048; i += 256){
    int p = i*4;
    int row = p >> 6, kgpos = (p >> 4) & 3, sub = (p >> 2) & 3;
    int kg = kgpos ^ ((row >> 1) & 3);
    int ke = kg*8 + 2*sub;
    float x0 = tile[ke][row], x1 = tile[ke+1][row];
    ushort h0 = f2bf(x0), h1 = f2bf(x1);
    ushort l0 = f2bf(x0 - bf2f(h0)), l1 = f2bf(x1 - bf2f(h1));
    hi_img[base + i] = (uint32_t)h0 | ((uint32_t)h1 << 16);
    lo_img[base + i] = (uint32_t)l0 | ((uint32_t)l1 << 16);
  }
}

// ---------------------------------------------------------------- f32 GEMM (MODE 0: +b ; MODE 1: tanh ; MODE 2: tanh + split)
template<int MODE>
__global__ __launch_bounds__(256) void gemm_f32_kernel(
    const float* __restrict__ X, const float* __restrict__ W, const float* __restrict__ bias,
    float* __restrict__ O1, ushort* __restrict__ O2, ushort* __restrict__ O3,
    int Kdim, int N)
{
  __shared__ float At[2][8][132];
  __shared__ float Bs[2][8][132];
  int tid = threadIdx.x;
  int n0 = blockIdx.x*128, r0 = blockIdx.y*128;
  int tx = tid & 15, ty = tid >> 4;
  int am = tid >> 1, akq = tid & 1;
  int bk = tid >> 5, bnc = tid & 31;
  float acc[8][8];
  #pragma unroll
  for (int i=0;i<8;i++)
    #pragma unroll
    for (int j=0;j<8;j++) acc[i][j]=0.f;
  {
    f32x4 av = *(const f32x4*)&X[(size_t)(r0+am)*Kdim + akq*4];
    At[0][akq*4+0][am]=av.x; At[0][akq*4+1][am]=av.y; At[0][akq*4+2][am]=av.z; At[0][akq*4+3][am]=av.w;
    int nb = n0 + bnc*4;
    f32x4 bv = {0.f,0.f,0.f,0.f};
    if (nb + 3 < N) bv = *(const f32x4*)&W[(size_t)bk*N + nb];
    *(f32x4*)&Bs[0][bk][bnc*4] = bv;
  }
  __syncthreads();
  int nk = Kdim >> 3;
  for (int ksb = 0; ksb < nk; ksb++){
    int cb = ksb & 1;
    if (ksb + 1 < nk){
      int k0 = (ksb+1)*8, bs = cb^1;
      f32x4 av = *(const f32x4*)&X[(size_t)(r0+am)*Kdim + k0 + akq*4];
      At[bs][akq*4+0][am]=av.x; At[bs][akq*4+1][am]=av.y; At[bs][akq*4+2][am]=av.z; At[bs][akq*4+3][am]=av.w;
      int nb = n0 + bnc*4;
      f32x4 bv = {0.f,0.f,0.f,0.f};
      if (nb + 3 < N) bv = *(const f32x4*)&W[(size_t)(k0+bk)*N + nb];
      *(f32x4*)&Bs[bs][bk][bnc*4] = bv;
    }
    #pragma unroll
    for (int k = 0; k < 8; k++){
      float a[8], b[8];
      *(f32x4*)&a[0] = *(const f32x4*)&At[cb][k][ty*8];
      *(f32x4*)&a[4] = *(const f32x4*)&At[cb][k][ty*8+4];
      *(f32x4*)&b[0] = *(const f32x4*)&Bs[cb][k][tx*8];
      *(f32x4*)&b[4] = *(const f32x4*)&Bs[cb][k][tx*8+4];
      #pragma unroll
      for (int i=0;i<8;i++)
        #pragma unroll
        for (int j=0;j<8;j++) acc[i][j] = fmaf(a[i], b[j], acc[i][j]);
    }
    __syncthreads();
  }
  #pragma unroll
  for (int i=0;i<8;i++){
    int r = r0 + ty*8 + i;
    #pragma unroll
    for (int j=0;j<8;j+=4){
      int n = n0 + tx*8 + j;
      if (n + 3 < N){
        f32x4 v;
        v.x = acc[i][j+0] + bias[n+0];
        v.y = acc[i][j+1] + bias[n+1];
        v.z = acc[i][j+2] + bias[n+2];
        v.w = acc[i][j+3] + bias[n+3];
        if (MODE >= 1){
          v.x = tanhf(v.x); v.y = tanhf(v.y); v.z = tanhf(v.z); v.w = tanhf(v.w);
        }
        *(f32x4*)&O1[(size_t)r*N + n] = v;
        if (MODE == 2){
          u16x4 h, l;
          #pragma unroll
          for (int q = 0; q < 4; q++){
            ushort hb = f2bf(v[q]);
            h[q] = hb;
            l[q] = f2bf(v[q] - bf2f(hb));
          }
          *(u16x4*)&O2[(size_t)r*N + n] = h;
          *(u16x4*)&O3[(size_t)r*N + n] = l;
        }
      }
    }
  }
}

// ---------------------------------------------------------------- ON-LSTM scan: redundant masters + all-poll-all barrier
__global__ __launch_bounds__(512) void scan_kernel(
    const float* __restrict__ A,
    const float* __restrict__ WhT,
    const float* __restrict__ WhmT,
    float* __restrict__ hbuf,
    float* __restrict__ H,
    float* __restrict__ cf_out, float* __restrict__ df_out,
    int* bar_flags)
{
  __shared__ __align__(16) float wls[1024*20];       // 80 KB: 16 gate cols
  __shared__ __align__(16) float hls[1024*12];       // 48 KB: h [k][8]
  __shared__ __align__(16) float gpw[2][2][32][36];  // 18 KB: gate partials; aliased as master scratch
  __shared__ float projg[8][16];
  __shared__ float cst[8][4];
  __shared__ float tfv[8][16], tiv[8][16];

  int tid = threadIdx.x, wg = blockIdx.x;
  int e0 = wg*4, chunk = wg >> 4;

  // one-time: 16 gate cols into LDS
  #pragma unroll
  for (int c = 0; c < 16; c++){
    int gcol = (c>>2)*1024 + e0 + (c&3);
    const float* src = WhT + (size_t)gcol*1024;
    for (int k = tid; k < 1024; k += 512)
      wls[k*20 + c] = src[k];
  }
  if (tid < 32) cst[tid & 7][tid >> 3] = 0.f;

  // fixed thread mappings
  int cq = tid >> 8;              // gate: 0..1 (8 cols)
  int bh = (tid >> 7) & 1;        // gate: 0..1 (4 b)
  int kp = tid & 127;             // gate: k-split
  int mb  = tid & 7;              // master: b
  int mcg = (tid >> 3) & 7;       // master: col group (4 cols)
  int mks = tid >> 6;             // master: k-split of 128
  float (*mscr)[8][8][4] = (float (*)[8][8][4])gpw;   // [b][cg][ks][c]

  // A prefetch for t=0
  float Ag = 0.f, Am = 0.f;
  if (tid < 128){
    int c = tid >> 3, b = tid & 7;
    Ag = A[(size_t)b*GATE + (c>>2)*1024 + e0 + (c&3)];
  }
  if (tid < 256){
    int b = tid >> 5, c = tid & 31;
    Am = A[(size_t)b*GATE + 4096 + c];
  }
  __syncthreads();

  for (int t = 0; t < TT; t++){
    int rb = (t+1) & 1, wb = t & 1;
    // P0: stage h(t-1)
    {
      const f32x4* hb4 = (const f32x4*)&hbuf[rb*8192];
      #pragma unroll
      for (int s2 = 0; s2 < 4; s2++){
        int i4 = s2*512 + tid;
        f32x4 v = hb4[i4];
        int k = i4 >> 1, h2 = i4 & 1;
        *(f32x4*)&hls[k*12 + h2*4] = v;
      }
    }
    __syncthreads();

    // M1: master dots (all WGs, all b): thread (mb,mcg,mks), 4 cols x 128 k
    {
      float macc0=0.f, macc1=0.f, macc2=0.f, macc3=0.f;
      int kb = mks*128;
      #pragma unroll 4
      for (int k = kb; k < kb + 128; k++){
        f32x4 wm = *(const f32x4*)&WhmT[k*32 + mcg*4];
        float hv = hls[k*12 + mb];
        macc0 = fmaf(wm.x, hv, macc0);
        macc1 = fmaf(wm.y, hv, macc1);
        macc2 = fmaf(wm.z, hv, macc2);
        macc3 = fmaf(wm.w, hv, macc3);
      }
      f32x4 v4 = { macc0, macc1, macc2, macc3 };
      *(f32x4*)&mscr[mb][mcg][mks][0] = v4;
    }
    __syncthreads();
    // M2: reduce + softmax + cumsum, fully in-lane (tid<256: b=tid>>5, c=tid&31)
    if (tid < 256){
      int b = tid >> 5, c = tid & 31;
      float s = Am;
      #pragma unroll
      for (int ks = 0; ks < 8; ks++) s += mscr[b][c>>2][ks][c&3];
      int half = (c >> 4), j = c & 15;
      float mx = s;
      #pragma unroll
      for (int o = 1; o < 16; o <<= 1) mx = fmaxf(mx, __shfl_xor(mx, o));
      float e = expf(s - mx);
      float ssum = e;
      #pragma unroll
      for (int o = 1; o < 16; o <<= 1) ssum += __shfl_xor(ssum, o);
      float sm = e / ssum;
      float cum = sm;
      #pragma unroll
      for (int o = 1; o < 16; o <<= 1){
        float t2 = __shfl_up(cum, o);
        if (j >= o) cum += t2;
      }
      if (half == 0) tfv[b][j] = cum; else tiv[b][j] = 1.f - cum;
      if (cf_out != nullptr && wg == 0 && half == 0){
        cf_out[(b*TT + t)*16 + j] = cum;
        float ts = cum;
        #pragma unroll
        for (int o = 1; o < 16; o <<= 1) ts += __shfl_xor(ts, o);
        if (j == 0) df_out[b*TT + t] = 16.f - ts;
      }
    }
    __syncthreads();

    // P1: gate dots from LDS
    float acc[8][4];
    #pragma unroll
    for (int c = 0; c < 8; c++)
      #pragma unroll
      for (int b2 = 0; b2 < 4; b2++) acc[c][b2] = 0.f;
    #pragma unroll
    for (int j = 0; j < 8; j++){
      int k = j*128 + kp;
      float wa[8], hb[4];
      *(f32x4*)&wa[0] = *(const f32x4*)&wls[k*20 + cq*8];
      *(f32x4*)&wa[4] = *(const f32x4*)&wls[k*20 + cq*8 + 4];
      *(f32x4*)&hb[0] = *(const f32x4*)&hls[k*12 + bh*4];
      #pragma unroll
      for (int c = 0; c < 8; c++)
        #pragma unroll
        for (int b2 = 0; b2 < 4; b2++)
          acc[c][b2] = fmaf(wa[c], hb[b2], acc[c][b2]);
    }
    #pragma unroll
    for (int c = 0; c < 8; c++)
      #pragma unroll
      for (int b2 = 0; b2 < 4; b2++){
        float v = acc[c][b2];
        v += __shfl_xor(v, 1);
        v += __shfl_xor(v, 2);
        acc[c][b2] = v;
      }
    if ((kp & 3) == 0){
      int kg = kp >> 2;
      #pragma unroll
      for (int c = 0; c < 8; c++){
        f32x4 v4 = { acc[c][0], acc[c][1], acc[c][2], acc[c][3] };
        *(f32x4*)&gpw[cq][bh][kg][c*4] = v4;
      }
    }
    __syncthreads();
    // P2: reduce + A
    if (tid < 128){
      int c = tid >> 3, b = tid & 7;
      float s = Ag;
      #pragma unroll
      for (int g = 0; g < 32; g++) s += gpw[c>>3][b>>2][g][(c&7)*4 + (b&3)];
      projg[b][c] = s;
    }
    __syncthreads();
    // P4: cell update (tf/ti from LDS)
    if (tid < 32){
      int b = tid & 7, e = tid >> 3;
      float gi = projg[b][e], gf = projg[b][4+e], go = projg[b][8+e], gg = projg[b][12+e];
      float iv = 1.f/(1.f+expf(-gi)), fv = 1.f/(1.f+expf(-gf)), ov = 1.f/(1.f+expf(-go));
      float gv = tanhf(gg);
      float tf = tfv[b][chunk], ti = tiv[b][chunk];
      float w  = tf*ti;
      float c2 = (fv*w + (tf - w))*cst[b][e] + (iv*w + (ti - w))*gv;
      cst[b][e] = c2;
      float h2 = ov * tanhf(c2);
      hbuf[wb*8192 + (e0+e)*8 + b] = h2;
      H[(size_t)(t*8+b)*1024 + e0 + e] = h2;
    }
    // A prefetch for t+1 (A static; issue before barrier to hide latency)
    if (t + 1 < TT){
      if (tid < 128){
        int c = tid >> 3, b = tid & 7;
        Ag = A[(size_t)((t+1)*8+b)*GATE + (c>>2)*1024 + e0 + (c&3)];
      }
      if (tid < 256){
        int b = tid >> 5, c = tid & 31;
        Am = A[(size_t)((t+1)*8+b)*GATE + 4096 + c];
      }
    }
    __syncthreads();
    // all-poll-all barrier: single leg
    if (tid == 0){
      __threadfence();
      __hip_atomic_store(&bar_flags[wg*16], t+1, __ATOMIC_RELAXED, __HIP_MEMORY_SCOPE_AGENT);
    }
    if (tid < NWG){
      while (__hip_atomic_load(&bar_flags[tid*16], __ATOMIC_RELAXED, __HIP_MEMORY_SCOPE_AGENT) < t+1)
        __builtin_amdgcn_s_sleep(1);
    }
    __syncthreads();
    if (tid == 0) __threadfence();   // acquire
    __syncthreads();
  }
}

// ---------------------------------------------------------------- split-bf16 MFMA GEMM (r11, unchanged)
__device__ __forceinline__ void stageA_lds(const ushort* gsrc, char* ldsbase, int row0, int k0, int tid){
  int lane = tid & 63, wv = tid >> 6;
  #pragma unroll
  for (int s = 0; s < 2; s++){
    int p = wv*1024 + s*4096 + lane*16;
    int row = p >> 6;
    int kg  = (p >> 4) & 3;
    int kgs = kg ^ ((row >> 1) & 3);
    const ushort* ga = gsrc + (size_t)(row0 + row)*1024 + k0 + kgs*8;
    __builtin_amdgcn_global_load_lds(
        (const __attribute__((address_space(1))) void*)ga,
        (__attribute__((address_space(3))) void*)(ldsbase + wv*1024 + s*4096),
        16, 0, 0);
  }
}
__device__ __forceinline__ void stageB_pre(const char* img, char* lds, int nt, int ks, int tid){
  int lane = tid & 63, wv = tid >> 6;
  const char* base = img + (((size_t)(nt*32 + ks)) << 13);
  #pragma unroll
  for (int s = 0; s < 2; s++){
    int p = wv*1024 + s*4096 + lane*16;
    __builtin_amdgcn_global_load_lds(
        (const __attribute__((address_space(1))) void*)(base + p),
        (__attribute__((address_space(3))) void*)(lds + p),
        16, 0, 0);
  }
}
__device__ __forceinline__ void stageB_cv(const float* __restrict__ Wo, int n0, int k0, int tid,
                                          char* bhi, char* blo){
  int kp = tid & 15, g = tid >> 4;
  const float* src = Wo + (size_t)(k0 + 2*kp)*VOC + n0 + g*8;
  f32x4 v00 = *(const f32x4*)(src);
  f32x4 v01 = *(const f32x4*)(src + 4);
  f32x4 v10 = *(const f32x4*)(src + VOC);
  f32x4 v11 = *(const f32x4*)(src + VOC + 4);
  int kg = kp >> 2, sub = kp & 3;
  #pragma unroll
  for (int j = 0; j < 8; j++){
    float x0 = (j < 4) ? v00[j] : v01[j-4];
    float x1 = (j < 4) ? v10[j] : v11[j-4];
    ushort h0 = f2bf(x0), h1 = f2bf(x1);
    ushort l0 = f2bf(x0 - bf2f(h0)), l1 = f2bf(x1 - bf2f(h1));
    int n = g*8 + j;
    int byte = n*64 + ((kg ^ ((n >> 1) & 3)) << 4) + sub*4;
    *(uint32_t*)(bhi + byte) = (uint32_t)h0 | ((uint32_t)h1 << 16);
    *(uint32_t*)(blo + byte) = (uint32_t)l0 | ((uint32_t)l1 << 16);
  }
}
__device__ __forceinline__ bf16x8 rdfrag(const char* base, int row, int kg){
  int byte = row*64 + ((kg ^ ((row >> 1) & 3)) << 4);
  return *(const bf16x8*)(base + byte);
}

template<int PRE>
__global__ __launch_bounds__(256) void wo_gemm_kernel(
    const ushort* __restrict__ Ahi, const ushort* __restrict__ Alo,
    const float* __restrict__ Wo, const float* __restrict__ bo,
    const char* __restrict__ wohi_img, const char* __restrict__ wolo_img,
    float* __restrict__ S, float* __restrict__ partials, int rowbase)
{
  __shared__ __align__(16) char smem[66560];
  __shared__ float bo_s[128];
  __shared__ float redm[128][2], reds[128][2];
  int tid = threadIdx.x;
  int nt = blockIdx.x, mt = blockIdx.y;
  int n0 = nt*128, row0loc = mt*128, row0 = rowbase + row0loc;
  if (tid < 128) bo_s[tid] = bo[n0 + tid];
  f32x4 acc[4][4] = {};

  stageA_lds(Ahi, smem + 0,    row0, 0, tid);
  stageA_lds(Alo, smem + 8192, row0, 0, tid);
  if (PRE){
    stageB_pre(wohi_img, smem + 16384, nt, 0, tid);
    stageB_pre(wolo_img, smem + 24576, nt, 0, tid);
  } else {
    stageB_cv(Wo, n0, 0, tid, smem + 16384, smem + 24576);
  }
  __syncthreads();

  int lane = tid & 63, wv = tid >> 6;
  int wr = wv >> 1, wc = wv & 1;
  int rl = lane & 15, kgl = lane >> 4;
  for (int ks = 0; ks < 32; ks++){
    char* cb = smem + (ks & 1)*32768;
    if (ks + 1 < 32){
      char* nb2 = smem + ((ks+1) & 1)*32768;
      stageA_lds(Ahi, nb2,        row0, (ks+1)*32, tid);
      stageA_lds(Alo, nb2 + 8192, row0, (ks+1)*32, tid);
      if (PRE){
        stageB_pre(wohi_img, nb2 + 16384, nt, ks+1, tid);
        stageB_pre(wolo_img, nb2 + 24576, nt, ks+1, tid);
      } else {
        stageB_cv(Wo, n0, (ks+1)*32, tid, nb2 + 16384, nb2 + 24576);
      }
    }
    bf16x8 ah[4], al[4], bh[4], bl2[4];
    #pragma unroll
    for (int m = 0; m < 4; m++){
      int row = wr*64 + m*16 + rl;
      ah[m] = rdfrag(cb,        row, kgl);
      al[m] = rdfrag(cb + 8192, row, kgl);
    }
    #pragma unroll
    for (int n = 0; n < 4; n++){
      int rw = wc*64 + n*16 + rl;
      bh[n]  = rdfrag(cb + 16384, rw, kgl);
      bl2[n] = rdfrag(cb + 24576, rw, kgl);
    }
    #pragma unroll
    for (int m = 0; m < 4; m++)
      #pragma unroll
      for (int n = 0; n < 4; n++){
        acc[m][n] = __builtin_amdgcn_mfma_f32_16x16x32_bf16(ah[m], bh[n],  acc[m][n], 0,0,0);
        acc[m][n] = __builtin_amdgcn_mfma_f32_16x16x32_bf16(ah[m], bl2[n], acc[m][n], 0,0,0);
        acc[m][n] = __builtin_amdgcn_mfma_f32_16x16x32_bf16(al[m], bh[n],  acc[m][n], 0,0,0);
      }
    __syncthreads();
  }

  float* st = (float*)smem;
  #pragma unroll
  for (int m = 0; m < 4; m++){
    int rb = wr*64 + m*16 + (lane >> 4)*4;
    #pragma unroll
    for (int n = 0; n < 4; n++){
      int col = wc*64 + n*16 + rl;
      #pragma unroll
      for (int j = 0; j < 4; j++)
        st[(rb + j)*130 + col] = acc[m][n][j];
    }
  }
  __syncthreads();
  int row = tid >> 1, half = tid & 1;
  float lmax = -1e30f;
  for (int jc = 0; jc < 64; jc += 4){
    f32x4 v;
    #pragma unroll
    for (int j = 0; j < 4; j++){
      float x = st[row*130 + half*64 + jc + j] + bo_s[half*64 + jc + j];
      st[row*130 + half*64 + jc + j] = x;
      v[j] = x;
      lmax = fmaxf(lmax, x);
    }
    *(f32x4*)&S[(size_t)(row0loc + row)*VOC + n0 + half*64 + jc] = v;
  }
  redm[row][half] = lmax;
  __syncthreads();
  float rm = fmaxf(redm[row][0], redm[row][1]);
  float lsum = 0.f;
  for (int jc = 0; jc < 64; jc++)
    lsum += expf(st[row*130 + half*64 + jc] - rm);
  reds[row][half] = lsum;
  __syncthreads();
  if (half == 0){
    float2 pr; pr.x = rm; pr.y = reds[row][0] + reds[row][1];
    *(float2*)&partials[((size_t)(row0loc + row)*250 + nt)*2] = pr;
  }
}

// ---------------------------------------------------------------- Z finalize
__global__ void zfin_kernel(const float* __restrict__ partials, double* __restrict__ Zc, int CH){
  int rl = blockIdx.x*256 + threadIdx.x;
  if (rl >= CH) return;
  float m = -1e30f;
  for (int t2 = 0; t2 < 250; t2++) m = fmaxf(m, partials[((size_t)rl*250 + t2)*2]);
  double s = 0.0;
  for (int t2 = 0; t2 < 250; t2++){
    float pm = partials[((size_t)rl*250 + t2)*2];
    float se = partials[((size_t)rl*250 + t2)*2 + 1];
    s += exp((double)pm - (double)m)*(double)se;
  }
  Zc[rl] = (double)m + log(s);
}

// ---------------------------------------------------------------- candidates: f32 argmax + 0.02 margin
__device__ __forceinline__ float cand_q(const float* __restrict__ srow, int v,
                                        float l0, float l1, float l2, float l3, float l4){
  float t0 = l0 + srow[v];
  float t1 = l1 + srow[VOC   + v];
  float t2 = l2 + srow[2*VOC + v];
  float t3 = l3 + srow[3*VOC + v];
  float t4 = l4 + srow[4*VOC + v];
  float m = fmaxf(fmaxf(fmaxf(t0,t1),fmaxf(t2,t3)),t4);
  return m + logf(expf(t0-m)+expf(t1-m)+expf(t2-m)+expf(t3-m)+expf(t4-m));
}
__global__ __launch_bounds__(256) void cand_kernel(
    const float* __restrict__ S, const double* __restrict__ lp, const double* __restrict__ Z,
    int* __restrict__ cand, int rbase)
{
  int g = blockIdx.x; int r = rbase + g; int tid = threadIdx.x;
  __shared__ float lpk[5];
  __shared__ float rq[256]; __shared__ int rv[256];
  __shared__ int cnt; __shared__ int list[64];
  if (tid < 5) lpk[tid] = (float)(lp[r*5 + tid] - Z[r*5 + tid]);
  if (tid == 0) cnt = 0;
  __syncthreads();
  float l0 = lpk[0], l1 = lpk[1], l2 = lpk[2], l3 = lpk[3], l4 = lpk[4];
  const float* srow = S + (size_t)(g*5)*VOC;
  float bq = -1e30f; int bv = 0;
  for (int v = tid; v < VOC; v += 256){
    float q = cand_q(srow, v, l0,l1,l2,l3,l4);
    if (q > bq){ bq = q; bv = v; }
  }
  rq[tid] = bq; rv[tid] = bv; __syncthreads();
  for (int s = 128; s > 0; s >>= 1){
    if (tid < s){
      if (rq[tid+s] > rq[tid] || (rq[tid+s] == rq[tid] && rv[tid+s] < rv[tid])){
        rq[tid] = rq[tid+s]; rv[tid] = rv[tid+s];
      }
    }
    __syncthreads();
  }
  float M = rq[0]; int argv = rv[0];
  for (int v = tid; v < VOC; v += 256){
    float q = cand_q(srow, v, l0,l1,l2,l3,l4);
    if (q >= M - 0.02f && v != argv){
      int ix = atomicAdd(&cnt, 1);
      if (ix < 63) list[ix] = v;
    }
  }
  __syncthreads();
  int nc = cnt < 63 ? cnt : 63;
  if (tid == 0){ cand[r*66] = nc + 1; cand[r*66 + 1] = argv; }
  if (tid < nc) cand[r*66 + 2 + tid] = list[tid];
}

// ---------------------------------------------------------------- exact f64 refinement: pred + gold nll
__global__ __launch_bounds__(256) void refine_kernel(
    const float* __restrict__ lat, const float* __restrict__ Wo, const float* __restrict__ bo,
    const double* __restrict__ lp, const double* __restrict__ Z,
    const int* __restrict__ cand, const int* __restrict__ ys,
    float* __restrict__ nll, float* __restrict__ pred_out)
{
  int r = blockIdx.x, tid = threadIdx.x;
  int b = r & 7, l = r >> 3;
  int nc = cand[r*66];
  if (nc < 0) nc = 0;
  if (nc > 64) nc = 64;
  __shared__ double dred[5][4];
  __shared__ double bestval; __shared__ int bestv;
  if (tid == 0){ bestval = -1e300; bestv = 0; }
  __syncthreads();
  int gold = ys[b*129 + l + 1];
  for (int ci = 0; ci <= nc; ci++){
    int v = (ci < nc) ? cand[r*66 + 1 + ci] : gold;
    double p0=0,p1=0,p2=0,p3=0,p4=0;
    for (int h = tid; h < 1024; h += 256){
      double w = (double)Wo[(size_t)h*VOC + v];
      p0 += (double)lat[((size_t)r*5+0)*1024 + h]*w;
      p1 += (double)lat[((size_t)r*5+1)*1024 + h]*w;
      p2 += (double)lat[((size_t)r*5+2)*1024 + h]*w;
      p3 += (double)lat[((size_t)r*5+3)*1024 + h]*w;
      p4 += (double)lat[((size_t)r*5+4)*1024 + h]*w;
    }
    #pragma unroll
    for (int off = 32; off; off >>= 1){
      p0 += __shfl_down(p0, off); p1 += __shfl_down(p1, off);
      p2 += __shfl_down(p2, off); p3 += __shfl_down(p3, off);
      p4 += __shfl_down(p4, off);
    }
    if ((tid & 63) == 0){
      int w = tid >> 6;
      dred[0][w]=p0; dred[1][w]=p1; dred[2][w]=p2; dred[3][w]=p3; dred[4][w]=p4;
    }
    __syncthreads();
    if (tid == 0){
      double bv = (double)bo[v];
      double tk[5]; double mx = -1e300;
      #pragma unroll
      for (int k = 0; k < 5; k++){
        double sk = dred[k][0]+dred[k][1]+dred[k][2]+dred[k][3] + bv;
        tk[k] = (lp[r*5+k] - Z[r*5+k]) + sk;
        mx = tk[k] > mx ? tk[k] : mx;
      }
      double q = mx + log(exp(tk[0]-mx)+exp(tk[1]-mx)+exp(tk[2]-mx)+exp(tk[3]-mx)+exp(tk[4]-mx));
      if (ci < nc){
        if (q > bestval || (q == bestval && v < bestv)){ bestval = q; bestv = v; }
      } else {
        nll[r] = (float)(-q);
      }
    }
    __syncthreads();
  }
  if (tid == 0) pred_out[b*TT + l] = (float)bestv;
}

// ---------------------------------------------------------------- prior
__global__ __launch_bounds__(64) void prior_kernel(
    const float* __restrict__ H2, const float* __restrict__ Wp, const float* __restrict__ bp,
    double* __restrict__ lp)
{
  int r = blockIdx.x, tid = threadIdx.x;
  double p0=0,p1=0,p2=0,p3=0,p4=0;
  for (int h = tid; h < 1024; h += 64){
    double x = (double)H2[(size_t)r*1024 + h];
    const float* w = &Wp[h*5];
    p0 += x*(double)w[0]; p1 += x*(double)w[1]; p2 += x*(double)w[2];
    p3 += x*(double)w[3]; p4 += x*(double)w[4];
  }
  #pragma unroll
  for (int off = 32; off; off >>= 1){
    p0 += __shfl_down(p0, off); p1 += __shfl_down(p1, off);
    p2 += __shfl_down(p2, off); p3 += __shfl_down(p3, off);
    p4 += __shfl_down(p4, off);
  }
  if (tid == 0){
    double lg[5] = { p0+(double)bp[0], p1+(double)bp[1], p2+(double)bp[2], p3+(double)bp[3], p4+(double)bp[4] };
    double mx = lg[0];
    #pragma unroll
    for (int k = 1; k < 5; k++) mx = lg[k] > mx ? lg[k] : mx;
    double s = 0;
    #pragma unroll
    for (int k = 0; k < 5; k++) s += exp(lg[k]-mx);
    double lse = mx + log(s);
    #pragma unroll
    for (int k = 0; k < 5; k++) lp[r*5+k] = lg[k] - lse;
  }
}

// ---------------------------------------------------------------- loss
__global__ void loss_kernel(const float* __restrict__ nll, const int* __restrict__ ys,
                            float* __restrict__ out){
  int tid = threadIdx.x;
  __shared__ float ps[8];
  if (tid < 8){
    float s = 0.f, ms = 0.f;
    for (int l = 0; l < TT; l++){
      int gold = ys[tid*129 + l + 1];
      float m = (gold != 0) ? 1.f : 0.f;
      s  += nll[l*8 + tid]*m;
      ms += m;
    }
    ps[tid] = s/(ms + 1e-13f);
  }
  __syncthreads();
  if (tid == 0){
    float t = 0.f;
    for (int b = 0; b < 8; b++) t += ps[b];
    out[0] = t/8.f;
  }
}

// ================================================================ launcher
extern "C" void kernel_launch(void* const* d_in, const int* in_sizes, int n_in,
                              void* d_out, int out_size, void* d_ws, size_t ws_size,
                              hipStream_t stream)
{
  (void)in_sizes; (void)n_in; (void)out_size;
  const int*   ys  = (const int*)  d_in[0];
  const float* emb = (const float*)d_in[1];
  const float* Wx0 = (const float*)d_in[2];
  const float* Wh0 = (const float*)d_in[3];
  const float* b0  = (const float*)d_in[4];
  const float* Wx1 = (const float*)d_in[5];
  const float* Wh1 = (const float*)d_in[6];
  const float* b1  = (const float*)d_in[7];
  const float* Wx2 = (const float*)d_in[8];
  const float* Wh2 = (const float*)d_in[9];
  const float* b2  = (const float*)d_in[10];
  const float* Wp  = (const float*)d_in[11];
  const float* bp  = (const float*)d_in[12];
  const float* Wl  = (const float*)d_in[13];
  const float* bl  = (const float*)d_in[14];
  const float* Wo  = (const float*)d_in[15];
  const float* bo  = (const float*)d_in[16];
  float* out = (float*)d_out;

  char* ws = (char*)d_ws;
  size_t off = 0;
  auto alloc = [&](size_t bytes){ size_t o = off; off += (bytes + 255) & ~(size_t)255; return o; };
  size_t o_hbuf = alloc(2*8192*4);
  size_t o_bars = alloc(3*NWG*16*sizeof(int));
  size_t zero_bytes = off;
  size_t o_x    = alloc((size_t)1024*512*4);
  size_t o_whT  = alloc((size_t)GATE*1024*4);
  size_t o_whmT = alloc((size_t)1024*32*4);
  size_t o_A    = alloc((size_t)1024*GATE*4);
  size_t o_H0   = alloc((size_t)1024*1024*4);
  size_t o_H1   = alloc((size_t)1024*1024*4);
  size_t o_H2   = alloc((size_t)1024*1024*4);
  size_t o_lp   = alloc((size_t)1024*5*8);
  size_t o_latf = alloc((size_t)1024*5120*4);
  size_t o_lath = alloc((size_t)5120*1024*2);
  size_t o_latl = alloc((size_t)5120*1024*2);
  size_t o_Z    = alloc((size_t)5120*8);
  size_t o_cand = alloc((size_t)1024*66*4);
  size_t o_nll  = alloc((size_t)1024*4);
  size_t base   = off;

  const size_t woimg = (size_t)250*32*8192;
  auto need = [&](int ch, int pre){
    return base + (pre ? 2*((woimg + 255) & ~(size_t)255) : 0)
                + (((size_t)ch*250*2*4 + 255) & ~(size_t)255)
                + (((size_t)ch*VOC*4 + 255) & ~(size_t)255);
  };
  int PRE, CH;
  if      (need(1280,1) <= ws_size){ PRE=1; CH=1280; }
  else if (need(640, 1) <= ws_size){ PRE=1; CH=640;  }
  else if (need(1280,0) <= ws_size){ PRE=0; CH=1280; }
  else                              { PRE=0; CH=640;  }
  size_t o_wohi = 0, o_wolo = 0;
  if (PRE){ o_wohi = alloc(woimg); o_wolo = alloc(woimg); }
  size_t o_part = alloc((size_t)CH*250*2*4);
  size_t o_s    = alloc((size_t)CH*VOC*4);
  (void)o_s;

  float*  hbuf  = (float*) (ws + o_hbuf);
  int*    bars  = (int*)   (ws + o_bars);
  float*  xbuf  = (float*) (ws + o_x);
  float*  whT   = (float*) (ws + o_whT);
  float*  whmT  = (float*) (ws + o_whmT);
  float*  Abuf  = (float*) (ws + o_A);
  float*  H0    = (float*) (ws + o_H0);
  float*  H1    = (float*) (ws + o_H1);
  float*  H2    = (float*) (ws + o_H2);
  double* lpbuf = (double*)(ws + o_lp);
  float*  latf  = (float*) (ws + o_latf);
  ushort* lath  = (ushort*)(ws + o_lath);
  ushort* latl  = (ushort*)(ws + o_latl);
  double* Zbuf  = (double*)(ws + o_Z);
  int*    candb = (int*)   (ws + o_cand);
  float*  nllb  = (float*) (ws + o_nll);
  char*   wohi  = ws + o_wohi;
  char*   wolo  = ws + o_wolo;
  float*  partb = (float*) (ws + o_part);
  float*  Sbuf  = (float*) (ws + o_s);

  int* flags0 = bars;
  int* flags1 = bars + NWG*16;
  int* flags2 = bars + 2*NWG*16;

  hipMemsetAsync(d_ws, 0, zero_bytes, stream);
  embed_kernel<<<1024, 128, 0, stream>>>(ys, emb, xbuf);
  if (PRE)
    wosplit_kernel<<<dim3(32,250), 256, 0, stream>>>(Wo, (uint32_t*)wohi, (uint32_t*)wolo);

  // layer 0
  gemm_f32_kernel<0><<<dim3(33,8), 256, 0, stream>>>(xbuf, Wx0, b0, Abuf, nullptr, nullptr, 512, GATE);
  whT_kernel<<<dim3(129,32), dim3(32,8), 0, stream>>>(Wh0, whT);
  whmT_kernel<<<128, 256, 0, stream>>>(Wh0, whmT);
  scan_kernel<<<NWG, 512, 0, stream>>>(Abuf, whT, whmT, hbuf, H0, nullptr, nullptr, flags0);
  // layer 1 (emits cf/df)
  gemm_f32_kernel<0><<<dim3(33,8), 256, 0, stream>>>(H0, Wx1, b1, Abuf, nullptr, nullptr, 1024, GATE);
  whT_kernel<<<dim3(129,32), dim3(32,8), 0, stream>>>(Wh1, whT);
  whmT_kernel<<<128, 256, 0, stream>>>(Wh1, whmT);
  hipMemsetAsync(hbuf, 0, 2*8192*4, stream);
  scan_kernel<<<NWG, 512, 0, stream>>>(Abuf, whT, whmT, hbuf, H1, out + 1025, out + 1, flags1);
  // layer 2
  gemm_f32_kernel<0><<<dim3(33,8), 256, 0, stream>>>(H1, Wx2, b2, Abuf, nullptr, nullptr, 1024, GATE);
  whT_kernel<<<dim3(129,32), dim3(32,8), 0, stream>>>(Wh2, whT);
  whmT_kernel<<<128, 256, 0, stream>>>(Wh2, whmT);
  hipMemsetAsync(hbuf, 0, 2*8192*4, stream);
  scan_kernel<<<NWG, 512, 0, stream>>>(Abuf, whT, whmT, hbuf, H2, nullptr, nullptr, flags2);

  prior_kernel<<<1024, 64, 0, stream>>>(H2, Wp, bp, lpbuf);
  gemm_f32_kernel<2><<<dim3(40,8), 256, 0, stream>>>(H2, Wl, bl, latf, lath, latl, 1024, 5120);

  int nchunks = 5120 / CH;
  for (int c = 0; c < nchunks; c++){
    if (PRE)
      wo_gemm_kernel<1><<<dim3(250, CH/128), 256, 0, stream>>>(lath, latl, Wo, bo, wohi, wolo, Sbuf, partb, c*CH);
    else
      wo_gemm_kernel<0><<<dim3(250, CH/128), 256, 0, stream>>>(lath, latl, Wo, bo, nullptr, nullptr, Sbuf, partb, c*CH);
    zfin_kernel<<<(CH + 255)/256, 256, 0, stream>>>(partb, Zbuf + c*CH, CH);
    cand_kernel<<<CH/5, 256, 0, stream>>>(Sbuf, lpbuf, Zbuf, candb, c*(CH/5));
  }
  refine_kernel<<<1024, 256, 0, stream>>>(latf, Wo, bo, lpbuf, Zbuf, candb, ys, nllb, out + 17409);
  loss_kernel<<<1, 64, 0, stream>>>(nllb, ys, out);
}

// Round 13
// 8965.385 us; speedup vs baseline: 1.4101x; 1.4101x over previous
//
#include <hip/hip_runtime.h>
#include <stdint.h>
#include <stddef.h>

#define TT   128
#define GATE 4128
#define VOC  32000
#define NWG  256

typedef float  f32x4 __attribute__((ext_vector_type(4)));
typedef short  bf16x8 __attribute__((ext_vector_type(8)));
typedef unsigned short u16x4 __attribute__((ext_vector_type(4)));

__device__ __forceinline__ float bf2f(ushort u){
  union { uint32_t i; float f; } c; c.i = ((uint32_t)u) << 16; return c.f;
}
__device__ __forceinline__ ushort f2bf(float x){
  uint32_t u = __builtin_bit_cast(uint32_t, x);
  uint32_t r = (u + 0x7fffu + ((u >> 16) & 1u)) >> 16;
  return (ushort)r;
}

// ---------------------------------------------------------------- embed
__global__ void embed_kernel(const int* __restrict__ ys, const float* __restrict__ emb,
                             float* __restrict__ x){
  int r = blockIdx.x;
  int t = r >> 3, b = r & 7;
  int tok = ys[b*129 + t];
  f32x4 v = *(const f32x4*)&emb[(size_t)tok*512 + threadIdx.x*4];
  *(f32x4*)&x[(size_t)r*512 + threadIdx.x*4] = v;
}

// ---------------------------------------------------------------- full Wh transpose
__global__ void whT_kernel(const float* __restrict__ Wh, float* __restrict__ WhT){
  __shared__ float tile[32][33];
  int g0 = blockIdx.x*32, k0 = blockIdx.y*32;
  int tx = threadIdx.x, ty = threadIdx.y;
  for (int i = ty; i < 32; i += 8)
    tile[i][tx] = Wh[(size_t)(k0+i)*GATE + g0 + tx];
  __syncthreads();
  for (int i = ty; i < 32; i += 8)
    WhT[(size_t)(g0+i)*1024 + k0 + tx] = tile[tx][i];
}

// ---------------------------------------------------------------- WhmT[k][c]
__global__ void whmT_kernel(const float* __restrict__ Wh, float* __restrict__ WhmT){
  int idx = blockIdx.x*256 + threadIdx.x;
  int k = idx >> 5, c = idx & 31;
  WhmT[idx] = Wh[(size_t)k*GATE + 4096 + c];
}

// ---------------------------------------------------------------- Wo -> pre-swizzled split-bf16 tile images
__global__ __launch_bounds__(256) void wosplit_kernel(const float* __restrict__ Wo,
                                                      uint32_t* __restrict__ hi_img,
                                                      uint32_t* __restrict__ lo_img){
  __shared__ float tile[32][132];
  int ks = blockIdx.x, nt = blockIdx.y;
  int tid = threadIdx.x;
  for (int i = tid; i < 4096; i += 256)
    tile[i>>7][i&127] = Wo[(size_t)(ks*32 + (i>>7))*VOC + nt*128 + (i&127)];
  __syncthreads();
  size_t base = ((size_t)(nt*32 + ks)) << 11;
  for (int i = tid; i < 2048; i += 256){
    int p = i*4;
    int row = p >> 6, kgpos = (p >> 4) & 3, sub = (p >> 2) & 3;
    int kg = kgpos ^ ((row >> 1) & 3);
    int ke = kg*8 + 2*sub;
    float x0 = tile[ke][row], x1 = tile[ke+1][row];
    ushort h0 = f2bf(x0), h1 = f2bf(x1);
    ushort l0 = f2bf(x0 - bf2f(h0)), l1 = f2bf(x1 - bf2f(h1));
    hi_img[base + i] = (uint32_t)h0 | ((uint32_t)h1 << 16);
    lo_img[base + i] = (uint32_t)l0 | ((uint32_t)l1 << 16);
  }
}

// ---------------------------------------------------------------- f32 GEMM (MODE 0: +b ; MODE 1: tanh ; MODE 2: tanh + split)
template<int MODE>
__global__ __launch_bounds__(256) void gemm_f32_kernel(
    const float* __restrict__ X, const float* __restrict__ W, const float* __restrict__ bias,
    float* __restrict__ O1, ushort* __restrict__ O2, ushort* __restrict__ O3,
    int Kdim, int N)
{
  __shared__ float At[2][8][132];
  __shared__ float Bs[2][8][132];
  int tid = threadIdx.x;
  int n0 = blockIdx.x*128, r0 = blockIdx.y*128;
  int tx = tid & 15, ty = tid >> 4;
  int am = tid >> 1, akq = tid & 1;
  int bk = tid >> 5, bnc = tid & 31;
  float acc[8][8];
  #pragma unroll
  for (int i=0;i<8;i++)
    #pragma unroll
    for (int j=0;j<8;j++) acc[i][j]=0.f;
  {
    f32x4 av = *(const f32x4*)&X[(size_t)(r0+am)*Kdim + akq*4];
    At[0][akq*4+0][am]=av.x; At[0][akq*4+1][am]=av.y; At[0][akq*4+2][am]=av.z; At[0][akq*4+3][am]=av.w;
    int nb = n0 + bnc*4;
    f32x4 bv = {0.f,0.f,0.f,0.f};
    if (nb + 3 < N) bv = *(const f32x4*)&W[(size_t)bk*N + nb];
    *(f32x4*)&Bs[0][bk][bnc*4] = bv;
  }
  __syncthreads();
  int nk = Kdim >> 3;
  for (int ksb = 0; ksb < nk; ksb++){
    int cb = ksb & 1;
    if (ksb + 1 < nk){
      int k0 = (ksb+1)*8, bs = cb^1;
      f32x4 av = *(const f32x4*)&X[(size_t)(r0+am)*Kdim + k0 + akq*4];
      At[bs][akq*4+0][am]=av.x; At[bs][akq*4+1][am]=av.y; At[bs][akq*4+2][am]=av.z; At[bs][akq*4+3][am]=av.w;
      int nb = n0 + bnc*4;
      f32x4 bv = {0.f,0.f,0.f,0.f};
      if (nb + 3 < N) bv = *(const f32x4*)&W[(size_t)(k0+bk)*N + nb];
      *(f32x4*)&Bs[bs][bk][bnc*4] = bv;
    }
    #pragma unroll
    for (int k = 0; k < 8; k++){
      float a[8], b[8];
      *(f32x4*)&a[0] = *(const f32x4*)&At[cb][k][ty*8];
      *(f32x4*)&a[4] = *(const f32x4*)&At[cb][k][ty*8+4];
      *(f32x4*)&b[0] = *(const f32x4*)&Bs[cb][k][tx*8];
      *(f32x4*)&b[4] = *(const f32x4*)&Bs[cb][k][tx*8+4];
      #pragma unroll
      for (int i=0;i<8;i++)
        #pragma unroll
        for (int j=0;j<8;j++) acc[i][j] = fmaf(a[i], b[j], acc[i][j]);
    }
    __syncthreads();
  }
  #pragma unroll
  for (int i=0;i<8;i++){
    int r = r0 + ty*8 + i;
    #pragma unroll
    for (int j=0;j<8;j+=4){
      int n = n0 + tx*8 + j;
      if (n + 3 < N){
        f32x4 v;
        v.x = acc[i][j+0] + bias[n+0];
        v.y = acc[i][j+1] + bias[n+1];
        v.z = acc[i][j+2] + bias[n+2];
        v.w = acc[i][j+3] + bias[n+3];
        if (MODE >= 1){
          v.x = tanhf(v.x); v.y = tanhf(v.y); v.z = tanhf(v.z); v.w = tanhf(v.w);
        }
        *(f32x4*)&O1[(size_t)r*N + n] = v;
        if (MODE == 2){
          u16x4 h, l;
          #pragma unroll
          for (int q = 0; q < 4; q++){
            ushort hb = f2bf(v[q]);
            h[q] = hb;
            l[q] = f2bf(v[q] - bf2f(hb));
          }
          *(u16x4*)&O2[(size_t)r*N + n] = h;
          *(u16x4*)&O3[(size_t)r*N + n] = l;
        }
      }
    }
  }
}

// ---------------------------------------------------------------- distributed-flag grid barrier (r11-proven)
__device__ __forceinline__ void gbar(int* flags, int* gen, int ep, int wg, int tid){
  if (wg == 0){
    if (tid == 0){
      __threadfence();
      __hip_atomic_store(&flags[0], ep, __ATOMIC_RELAXED, __HIP_MEMORY_SCOPE_AGENT);
    }
    if (tid < NWG){
      while (__hip_atomic_load(&flags[tid*16], __ATOMIC_RELAXED, __HIP_MEMORY_SCOPE_AGENT) < ep)
        __builtin_amdgcn_s_sleep(1);
    }
    __syncthreads();
    if (tid == 0){
      __threadfence();
      __hip_atomic_store(gen, ep, __ATOMIC_RELAXED, __HIP_MEMORY_SCOPE_AGENT);
      __threadfence();
    }
  } else {
    if (tid == 0){
      __threadfence();
      __hip_atomic_store(&flags[wg*16], ep, __ATOMIC_RELAXED, __HIP_MEMORY_SCOPE_AGENT);
      while (__hip_atomic_load(gen, __ATOMIC_RELAXED, __HIP_MEMORY_SCOPE_AGENT) < ep)
        __builtin_amdgcn_s_sleep(2);
      __threadfence();
    }
  }
}

// ---------------------------------------------------------------- ON-LSTM scan (r11 exact: LDS gate weights, 8 master WGs, parallel softmax)
__global__ __launch_bounds__(512) void scan_kernel(
    const float* __restrict__ A,
    const float* __restrict__ WhT,
    const float* __restrict__ WhmT,
    float* __restrict__ hbuf,
    float* __restrict__ H,
    float* __restrict__ cf_out, float* __restrict__ df_out,
    int* bar_flags, int* bar_gen, int* mflags, float* tfti)
{
  __shared__ __align__(16) float wls[1024*20];
  __shared__ __align__(16) float hls[1024*12];
  __shared__ __align__(16) float gpw[2][2][32][36];
  __shared__ float projg[8][16];
  __shared__ float cst[8][4];
  __shared__ float mpart[8][8][4];
  __shared__ float projmb[32];

  int tid = threadIdx.x, wg = blockIdx.x;
  int e0 = wg*4, chunk = wg >> 4;

  #pragma unroll
  for (int c = 0; c < 16; c++){
    int gcol = (c>>2)*1024 + e0 + (c&3);
    const float* src = WhT + (size_t)gcol*1024;
    for (int k = tid; k < 1024; k += 512)
      wls[k*20 + c] = src[k];
  }
  if (tid < 32) cst[tid & 7][tid >> 3] = 0.f;
  __syncthreads();

  int cq = tid >> 8;
  int bh = (tid >> 7) & 1;
  int kp = tid & 127;
  bool isM = (wg < 8);
  int mcg = tid & 7, mkp = tid >> 3;

  for (int t = 0; t < TT; t++){
    int rb = (t+1) & 1, wb = t & 1;
    float Ag = 0.f;
    if (tid < 128){
      int c = tid >> 3, b = tid & 7;
      Ag = A[(size_t)(t*8+b)*GATE + (c>>2)*1024 + e0 + (c&3)];
    }
    float Am = 0.f;
    if (isM && tid < 32) Am = A[(size_t)(t*8+wg)*GATE + 4096 + tid];

    {
      const f32x4* hb4 = (const f32x4*)&hbuf[rb*8192];
      #pragma unroll
      for (int s2 = 0; s2 < 4; s2++){
        int i4 = s2*512 + tid;
        f32x4 v = hb4[i4];
        int k = i4 >> 1, h2 = i4 & 1;
        *(f32x4*)&hls[k*12 + h2*4] = v;
      }
    }
    __syncthreads();

    if (isM){
      float macc[4] = {0.f,0.f,0.f,0.f};
      #pragma unroll
      for (int j = 0; j < 16; j++){
        int k = j*64 + mkp;
        f32x4 wm = *(const f32x4*)&WhmT[k*32 + mcg*4];
        float hv = hls[k*12 + wg];
        macc[0] += wm.x*hv; macc[1] += wm.y*hv; macc[2] += wm.z*hv; macc[3] += wm.w*hv;
      }
      #pragma unroll
      for (int off = 8; off < 64; off <<= 1){
        macc[0] += __shfl_xor(macc[0], off);
        macc[1] += __shfl_xor(macc[1], off);
        macc[2] += __shfl_xor(macc[2], off);
        macc[3] += __shfl_xor(macc[3], off);
      }
      if ((tid & 63) < 8){
        int wv = tid >> 6;
        mpart[wv][mcg][0] = macc[0]; mpart[wv][mcg][1] = macc[1];
        mpart[wv][mcg][2] = macc[2]; mpart[wv][mcg][3] = macc[3];
      }
      __syncthreads();
      if (tid < 32){
        float s = Am;
        #pragma unroll
        for (int wv = 0; wv < 8; wv++) s += mpart[wv][tid>>2][tid&3];
        projmb[tid] = s;
      }
      __syncthreads();
      // parallel softmax + cumsum over 32 lanes (lanes 0-15 mf, 16-31 mi)
      if (tid < 32){
        int half = tid >> 4, j = tid & 15;
        float x = projmb[tid];
        float mx = x;
        #pragma unroll
        for (int o = 1; o < 16; o <<= 1) mx = fmaxf(mx, __shfl_xor(mx, o));
        float e = expf(x - mx);
        float ssum = e;
        #pragma unroll
        for (int o = 1; o < 16; o <<= 1) ssum += __shfl_xor(ssum, o);
        float sm = e / ssum;
        float c = sm;
        #pragma unroll
        for (int o = 1; o < 16; o <<= 1){
          float t2 = __shfl_up(c, o);
          if (j >= o) c += t2;
        }
        float outv = half ? (1.f - c) : c;
        tfti[half*128 + wg*16 + j] = outv;
        if (cf_out != nullptr && half == 0){
          cf_out[(wg*TT + t)*16 + j] = c;
          float ts = c;
          #pragma unroll
          for (int o = 1; o < 16; o <<= 1) ts += __shfl_xor(ts, o);
          if (j == 0) df_out[wg*TT + t] = 16.f - ts;
        }
      }
      __syncthreads();
      if (tid == 0){
        __threadfence();
        __hip_atomic_store(&mflags[wg*16], t+1, __ATOMIC_RELAXED, __HIP_MEMORY_SCOPE_AGENT);
      }
    }

    float acc[8][4];
    #pragma unroll
    for (int c = 0; c < 8; c++)
      #pragma unroll
      for (int b2 = 0; b2 < 4; b2++) acc[c][b2] = 0.f;
    #pragma unroll
    for (int j = 0; j < 8; j++){
      int k = j*128 + kp;
      float wa[8], hb[4];
      *(f32x4*)&wa[0] = *(const f32x4*)&wls[k*20 + cq*8];
      *(f32x4*)&wa[4] = *(const f32x4*)&wls[k*20 + cq*8 + 4];
      *(f32x4*)&hb[0] = *(const f32x4*)&hls[k*12 + bh*4];
      #pragma unroll
      for (int c = 0; c < 8; c++)
        #pragma unroll
        for (int b2 = 0; b2 < 4; b2++)
          acc[c][b2] = fmaf(wa[c], hb[b2], acc[c][b2]);
    }
    #pragma unroll
    for (int c = 0; c < 8; c++)
      #pragma unroll
      for (int b2 = 0; b2 < 4; b2++){
        float v = acc[c][b2];
        v += __shfl_xor(v, 1);
        v += __shfl_xor(v, 2);
        acc[c][b2] = v;
      }
    if ((kp & 3) == 0){
      int kg = kp >> 2;
      #pragma unroll
      for (int c = 0; c < 8; c++){
        f32x4 v4 = { acc[c][0], acc[c][1], acc[c][2], acc[c][3] };
        *(f32x4*)&gpw[cq][bh][kg][c*4] = v4;
      }
    }
    __syncthreads();
    if (tid < 128){
      int c = tid >> 3, b = tid & 7;
      float s = Ag;
      #pragma unroll
      for (int g = 0; g < 32; g++) s += gpw[c>>3][b>>2][g][(c&7)*4 + (b&3)];
      projg[b][c] = s;
    }
    if (tid < 8){
      while (__hip_atomic_load(&mflags[tid*16], __ATOMIC_RELAXED, __HIP_MEMORY_SCOPE_AGENT) < t+1)
        __builtin_amdgcn_s_sleep(1);
    }
    __syncthreads();
    if (tid < 32){
      int b = tid & 7, e = tid >> 3;
      float gi = projg[b][e], gf = projg[b][4+e], go = projg[b][8+e], gg = projg[b][12+e];
      float iv = 1.f/(1.f+expf(-gi)), fv = 1.f/(1.f+expf(-gf)), ov = 1.f/(1.f+expf(-go));
      float gv = tanhf(gg);
      float tf = __hip_atomic_load(&tfti[b*16 + chunk],       __ATOMIC_RELAXED, __HIP_MEMORY_SCOPE_AGENT);
      float ti = __hip_atomic_load(&tfti[128 + b*16 + chunk], __ATOMIC_RELAXED, __HIP_MEMORY_SCOPE_AGENT);
      float w  = tf*ti;
      float c2 = (fv*w + (tf - w))*cst[b][e] + (iv*w + (ti - w))*gv;
      cst[b][e] = c2;
      float h2 = ov * tanhf(c2);
      hbuf[wb*8192 + (e0+e)*8 + b] = h2;
      H[(size_t)(t*8+b)*1024 + e0 + e] = h2;
    }
    __syncthreads();
    gbar(bar_flags, bar_gen, t+1, wg, tid);
    __syncthreads();
  }
}

// ---------------------------------------------------------------- split-bf16 MFMA GEMM (r11, unchanged)
__device__ __forceinline__ void stageA_lds(const ushort* gsrc, char* ldsbase, int row0, int k0, int tid){
  int lane = tid & 63, wv = tid >> 6;
  #pragma unroll
  for (int s = 0; s < 2; s++){
    int p = wv*1024 + s*4096 + lane*16;
    int row = p >> 6;
    int kg  = (p >> 4) & 3;
    int kgs = kg ^ ((row >> 1) & 3);
    const ushort* ga = gsrc + (size_t)(row0 + row)*1024 + k0 + kgs*8;
    __builtin_amdgcn_global_load_lds(
        (const __attribute__((address_space(1))) void*)ga,
        (__attribute__((address_space(3))) void*)(ldsbase + wv*1024 + s*4096),
        16, 0, 0);
  }
}
__device__ __forceinline__ void stageB_pre(const char* img, char* lds, int nt, int ks, int tid){
  int lane = tid & 63, wv = tid >> 6;
  const char* base = img + (((size_t)(nt*32 + ks)) << 13);
  #pragma unroll
  for (int s = 0; s < 2; s++){
    int p = wv*1024 + s*4096 + lane*16;
    __builtin_amdgcn_global_load_lds(
        (const __attribute__((address_space(1))) void*)(base + p),
        (__attribute__((address_space(3))) void*)(lds + p),
        16, 0, 0);
  }
}
__device__ __forceinline__ void stageB_cv(const float* __restrict__ Wo, int n0, int k0, int tid,
                                          char* bhi, char* blo){
  int kp = tid & 15, g = tid >> 4;
  const float* src = Wo + (size_t)(k0 + 2*kp)*VOC + n0 + g*8;
  f32x4 v00 = *(const f32x4*)(src);
  f32x4 v01 = *(const f32x4*)(src + 4);
  f32x4 v10 = *(const f32x4*)(src + VOC);
  f32x4 v11 = *(const f32x4*)(src + VOC + 4);
  int kg = kp >> 2, sub = kp & 3;
  #pragma unroll
  for (int j = 0; j < 8; j++){
    float x0 = (j < 4) ? v00[j] : v01[j-4];
    float x1 = (j < 4) ? v10[j] : v11[j-4];
    ushort h0 = f2bf(x0), h1 = f2bf(x1);
    ushort l0 = f2bf(x0 - bf2f(h0)), l1 = f2bf(x1 - bf2f(h1));
    int n = g*8 + j;
    int byte = n*64 + ((kg ^ ((n >> 1) & 3)) << 4) + sub*4;
    *(uint32_t*)(bhi + byte) = (uint32_t)h0 | ((uint32_t)h1 << 16);
    *(uint32_t*)(blo + byte) = (uint32_t)l0 | ((uint32_t)l1 << 16);
  }
}
__device__ __forceinline__ bf16x8 rdfrag(const char* base, int row, int kg){
  int byte = row*64 + ((kg ^ ((row >> 1) & 3)) << 4);
  return *(const bf16x8*)(base + byte);
}

template<int PRE>
__global__ __launch_bounds__(256) void wo_gemm_kernel(
    const ushort* __restrict__ Ahi, const ushort* __restrict__ Alo,
    const float* __restrict__ Wo, const float* __restrict__ bo,
    const char* __restrict__ wohi_img, const char* __restrict__ wolo_img,
    float* __restrict__ S, float* __restrict__ partials, int rowbase)
{
  __shared__ __align__(16) char smem[66560];
  __shared__ float bo_s[128];
  __shared__ float redm[128][2], reds[128][2];
  int tid = threadIdx.x;
  int nt = blockIdx.x, mt = blockIdx.y;
  int n0 = nt*128, row0loc = mt*128, row0 = rowbase + row0loc;
  if (tid < 128) bo_s[tid] = bo[n0 + tid];
  f32x4 acc[4][4] = {};

  stageA_lds(Ahi, smem + 0,    row0, 0, tid);
  stageA_lds(Alo, smem + 8192, row0, 0, tid);
  if (PRE){
    stageB_pre(wohi_img, smem + 16384, nt, 0, tid);
    stageB_pre(wolo_img, smem + 24576, nt, 0, tid);
  } else {
    stageB_cv(Wo, n0, 0, tid, smem + 16384, smem + 24576);
  }
  __syncthreads();

  int lane = tid & 63, wv = tid >> 6;
  int wr = wv >> 1, wc = wv & 1;
  int rl = lane & 15, kgl = lane >> 4;
  for (int ks = 0; ks < 32; ks++){
    char* cb = smem + (ks & 1)*32768;
    if (ks + 1 < 32){
      char* nb2 = smem + ((ks+1) & 1)*32768;
      stageA_lds(Ahi, nb2,        row0, (ks+1)*32, tid);
      stageA_lds(Alo, nb2 + 8192, row0, (ks+1)*32, tid);
      if (PRE){
        stageB_pre(wohi_img, nb2 + 16384, nt, ks+1, tid);
        stageB_pre(wolo_img, nb2 + 24576, nt, ks+1, tid);
      } else {
        stageB_cv(Wo, n0, (ks+1)*32, tid, nb2 + 16384, nb2 + 24576);
      }
    }
    bf16x8 ah[4], al[4], bh[4], bl2[4];
    #pragma unroll
    for (int m = 0; m < 4; m++){
      int row = wr*64 + m*16 + rl;
      ah[m] = rdfrag(cb,        row, kgl);
      al[m] = rdfrag(cb + 8192, row, kgl);
    }
    #pragma unroll
    for (int n = 0; n < 4; n++){
      int rw = wc*64 + n*16 + rl;
      bh[n]  = rdfrag(cb + 16384, rw, kgl);
      bl2[n] = rdfrag(cb + 24576, rw, kgl);
    }
    #pragma unroll
    for (int m = 0; m < 4; m++)
      #pragma unroll
      for (int n = 0; n < 4; n++){
        acc[m][n] = __builtin_amdgcn_mfma_f32_16x16x32_bf16(ah[m], bh[n],  acc[m][n], 0,0,0);
        acc[m][n] = __builtin_amdgcn_mfma_f32_16x16x32_bf16(ah[m], bl2[n], acc[m][n], 0,0,0);
        acc[m][n] = __builtin_amdgcn_mfma_f32_16x16x32_bf16(al[m], bh[n],  acc[m][n], 0,0,0);
      }
    __syncthreads();
  }

  float* st = (float*)smem;
  #pragma unroll
  for (int m = 0; m < 4; m++){
    int rb = wr*64 + m*16 + (lane >> 4)*4;
    #pragma unroll
    for (int n = 0; n < 4; n++){
      int col = wc*64 + n*16 + rl;
      #pragma unroll
      for (int j = 0; j < 4; j++)
        st[(rb + j)*130 + col] = acc[m][n][j];
    }
  }
  __syncthreads();
  int row = tid >> 1, half = tid & 1;
  float lmax = -1e30f;
  for (int jc = 0; jc < 64; jc += 4){
    f32x4 v;
    #pragma unroll
    for (int j = 0; j < 4; j++){
      float x = st[row*130 + half*64 + jc + j] + bo_s[half*64 + jc + j];
      st[row*130 + half*64 + jc + j] = x;
      v[j] = x;
      lmax = fmaxf(lmax, x);
    }
    *(f32x4*)&S[(size_t)(row0loc + row)*VOC + n0 + half*64 + jc] = v;
  }
  redm[row][half] = lmax;
  __syncthreads();
  float rm = fmaxf(redm[row][0], redm[row][1]);
  float lsum = 0.f;
  for (int jc = 0; jc < 64; jc++)
    lsum += expf(st[row*130 + half*64 + jc] - rm);
  reds[row][half] = lsum;
  __syncthreads();
  if (half == 0){
    float2 pr; pr.x = rm; pr.y = reds[row][0] + reds[row][1];
    *(float2*)&partials[((size_t)(row0loc + row)*250 + nt)*2] = pr;
  }
}

// ---------------------------------------------------------------- candidates (+fused Z finalize): f32 argmax + 0.02 margin
__device__ __forceinline__ float cand_q(const float* __restrict__ srow, int v,
                                        float l0, float l1, float l2, float l3, float l4){
  float t0 = l0 + srow[v];
  float t1 = l1 + srow[VOC   + v];
  float t2 = l2 + srow[2*VOC + v];
  float t3 = l3 + srow[3*VOC + v];
  float t4 = l4 + srow[4*VOC + v];
  float m = fmaxf(fmaxf(fmaxf(t0,t1),fmaxf(t2,t3)),t4);
  return m + logf(expf(t0-m)+expf(t1-m)+expf(t2-m)+expf(t3-m)+expf(t4-m));
}
__global__ __launch_bounds__(256) void cand_kernel(
    const float* __restrict__ S, const double* __restrict__ lp,
    const float* __restrict__ partials, double* __restrict__ Zd,
    int* __restrict__ cand, int rbase)
{
  int g = blockIdx.x; int r = rbase + g; int tid = threadIdx.x;
  __shared__ float lpk[5];
  __shared__ double zk[5];
  __shared__ float rq[256]; __shared__ int rv[256];
  __shared__ double rd[256];
  __shared__ int cnt; __shared__ int list[64];
  if (tid == 0) cnt = 0;
  // fused Z finalize for the 5 rows this block owns (lrow = g*5+k)
  for (int k = 0; k < 5; k++){
    size_t lrow = (size_t)(g*5 + k);
    float m = -1e30f;
    for (int t2 = tid; t2 < 250; t2 += 256) m = fmaxf(m, partials[(lrow*250 + t2)*2]);
    rq[tid] = m; __syncthreads();
    for (int s = 128; s; s >>= 1){ if (tid < s) rq[tid] = fmaxf(rq[tid], rq[tid+s]); __syncthreads(); }
    float M = rq[0]; __syncthreads();
    double ssum = 0.0;
    for (int t2 = tid; t2 < 250; t2 += 256){
      float pm = partials[(lrow*250 + t2)*2];
      float se = partials[(lrow*250 + t2)*2 + 1];
      ssum += exp((double)pm - (double)M)*(double)se;
    }
    rd[tid] = ssum; __syncthreads();
    for (int s = 128; s; s >>= 1){ if (tid < s) rd[tid] += rd[tid+s]; __syncthreads(); }
    if (tid == 0){
      double z = (double)M + log(rd[0]);
      zk[k] = z;
      Zd[lrow] = z;
    }
    __syncthreads();
  }
  if (tid < 5) lpk[tid] = (float)(lp[r*5 + tid] - zk[tid]);
  __syncthreads();
  float l0 = lpk[0], l1 = lpk[1], l2 = lpk[2], l3 = lpk[3], l4 = lpk[4];
  const float* srow = S + (size_t)(g*5)*VOC;
  float bq = -1e30f; int bv = 0;
  for (int v = tid; v < VOC; v += 256){
    float q = cand_q(srow, v, l0,l1,l2,l3,l4);
    if (q > bq){ bq = q; bv = v; }
  }
  rq[tid] = bq; rv[tid] = bv; __syncthreads();
  for (int s = 128; s > 0; s >>= 1){
    if (tid < s){
      if (rq[tid+s] > rq[tid] || (rq[tid+s] == rq[tid] && rv[tid+s] < rv[tid])){
        rq[tid] = rq[tid+s]; rv[tid] = rv[tid+s];
      }
    }
    __syncthreads();
  }
  float M = rq[0]; int argv = rv[0];
  for (int v = tid; v < VOC; v += 256){
    float q = cand_q(srow, v, l0,l1,l2,l3,l4);
    if (q >= M - 0.02f && v != argv){
      int ix = atomicAdd(&cnt, 1);
      if (ix < 63) list[ix] = v;
    }
  }
  __syncthreads();
  int nc = cnt < 63 ? cnt : 63;
  if (tid == 0){ cand[r*66] = nc + 1; cand[r*66 + 1] = argv; }
  if (tid < nc) cand[r*66 + 2 + tid] = list[tid];
}

// ---------------------------------------------------------------- exact f64 refinement: pred + gold nll
__global__ __launch_bounds__(256) void refine_kernel(
    const float* __restrict__ lat, const float* __restrict__ Wo, const float* __restrict__ bo,
    const double* __restrict__ lp, const double* __restrict__ Z,
    const int* __restrict__ cand, const int* __restrict__ ys,
    float* __restrict__ nll, float* __restrict__ pred_out)
{
  int r = blockIdx.x, tid = threadIdx.x;
  int b = r & 7, l = r >> 3;
  int nc = cand[r*66];
  if (nc < 0) nc = 0;
  if (nc > 64) nc = 64;
  __shared__ double dred[5][4];
  __shared__ double bestval; __shared__ int bestv;
  if (tid == 0){ bestval = -1e300; bestv = 0; }
  __syncthreads();
  int gold = ys[b*129 + l + 1];
  for (int ci = 0; ci <= nc; ci++){
    int v = (ci < nc) ? cand[r*66 + 1 + ci] : gold;
    double p0=0,p1=0,p2=0,p3=0,p4=0;
    for (int h = tid; h < 1024; h += 256){
      double w = (double)Wo[(size_t)h*VOC + v];
      p0 += (double)lat[((size_t)r*5+0)*1024 + h]*w;
      p1 += (double)lat[((size_t)r*5+1)*1024 + h]*w;
      p2 += (double)lat[((size_t)r*5+2)*1024 + h]*w;
      p3 += (double)lat[((size_t)r*5+3)*1024 + h]*w;
      p4 += (double)lat[((size_t)r*5+4)*1024 + h]*w;
    }
    #pragma unroll
    for (int off = 32; off; off >>= 1){
      p0 += __shfl_down(p0, off); p1 += __shfl_down(p1, off);
      p2 += __shfl_down(p2, off); p3 += __shfl_down(p3, off);
      p4 += __shfl_down(p4, off);
    }
    if ((tid & 63) == 0){
      int w = tid >> 6;
      dred[0][w]=p0; dred[1][w]=p1; dred[2][w]=p2; dred[3][w]=p3; dred[4][w]=p4;
    }
    __syncthreads();
    if (tid == 0){
      double bv = (double)bo[v];
      double tk[5]; double mx = -1e300;
      #pragma unroll
      for (int k = 0; k < 5; k++){
        double sk = dred[k][0]+dred[k][1]+dred[k][2]+dred[k][3] + bv;
        tk[k] = (lp[r*5+k] - Z[r*5+k]) + sk;
        mx = tk[k] > mx ? tk[k] : mx;
      }
      double q = mx + log(exp(tk[0]-mx)+exp(tk[1]-mx)+exp(tk[2]-mx)+exp(tk[3]-mx)+exp(tk[4]-mx));
      if (ci < nc){
        if (q > bestval || (q == bestval && v < bestv)){ bestval = q; bestv = v; }
      } else {
        nll[r] = (float)(-q);
      }
    }
    __syncthreads();
  }
  if (tid == 0) pred_out[b*TT + l] = (float)bestv;
}

// ---------------------------------------------------------------- prior
__global__ __launch_bounds__(64) void prior_kernel(
    const float* __restrict__ H2, const float* __restrict__ Wp, const float* __restrict__ bp,
    double* __restrict__ lp)
{
  int r = blockIdx.x, tid = threadIdx.x;
  double p0=0,p1=0,p2=0,p3=0,p4=0;
  for (int h = tid; h < 1024; h += 64){
    double x = (double)H2[(size_t)r*1024 + h];
    const float* w = &Wp[h*5];
    p0 += x*(double)w[0]; p1 += x*(double)w[1]; p2 += x*(double)w[2];
    p3 += x*(double)w[3]; p4 += x*(double)w[4];
  }
  #pragma unroll
  for (int off = 32; off; off >>= 1){
    p0 += __shfl_down(p0, off); p1 += __shfl_down(p1, off);
    p2 += __shfl_down(p2, off); p3 += __shfl_down(p3, off);
    p4 += __shfl_down(p4, off);
  }
  if (tid == 0){
    double lg[5] = { p0+(double)bp[0], p1+(double)bp[1], p2+(double)bp[2], p3+(double)bp[3], p4+(double)bp[4] };
    double mx = lg[0];
    #pragma unroll
    for (int k = 1; k < 5; k++) mx = lg[k] > mx ? lg[k] : mx;
    double s = 0;
    #pragma unroll
    for (int k = 0; k < 5; k++) s += exp(lg[k]-mx);
    double lse = mx + log(s);
    #pragma unroll
    for (int k = 0; k < 5; k++) lp[r*5+k] = lg[k] - lse;
  }
}

// ---------------------------------------------------------------- loss
__global__ void loss_kernel(const float* __restrict__ nll, const int* __restrict__ ys,
                            float* __restrict__ out){
  int tid = threadIdx.x;
  __shared__ float ps[8];
  if (tid < 8){
    float s = 0.f, ms = 0.f;
    for (int l = 0; l < TT; l++){
      int gold = ys[tid*129 + l + 1];
      float m = (gold != 0) ? 1.f : 0.f;
      s  += nll[l*8 + tid]*m;
      ms += m;
    }
    ps[tid] = s/(ms + 1e-13f);
  }
  __syncthreads();
  if (tid == 0){
    float t = 0.f;
    for (int b = 0; b < 8; b++) t += ps[b];
    out[0] = t/8.f;
  }
}

// ================================================================ launcher
extern "C" void kernel_launch(void* const* d_in, const int* in_sizes, int n_in,
                              void* d_out, int out_size, void* d_ws, size_t ws_size,
                              hipStream_t stream)
{
  (void)in_sizes; (void)n_in; (void)out_size;
  const int*   ys  = (const int*)  d_in[0];
  const float* emb = (const float*)d_in[1];
  const float* Wx0 = (const float*)d_in[2];
  const float* Wh0 = (const float*)d_in[3];
  const float* b0  = (const float*)d_in[4];
  const float* Wx1 = (const float*)d_in[5];
  const float* Wh1 = (const float*)d_in[6];
  const float* b1  = (const float*)d_in[7];
  const float* Wx2 = (const float*)d_in[8];
  const float* Wh2 = (const float*)d_in[9];
  const float* b2  = (const float*)d_in[10];
  const float* Wp  = (const float*)d_in[11];
  const float* bp  = (const float*)d_in[12];
  const float* Wl  = (const float*)d_in[13];
  const float* bl  = (const float*)d_in[14];
  const float* Wo  = (const float*)d_in[15];
  const float* bo  = (const float*)d_in[16];
  float* out = (float*)d_out;

  char* ws = (char*)d_ws;
  size_t off = 0;
  auto alloc = [&](size_t bytes){ size_t o = off; off += (bytes + 255) & ~(size_t)255; return o; };
  size_t o_hbuf = alloc(2*8192*4);
  size_t o_bars = alloc(3*(NWG*16 + 16)*sizeof(int));
  size_t o_mfl  = alloc(3*8*16*sizeof(int));
  size_t zero_bytes = off;
  size_t o_tfti = alloc(256*4);
  size_t o_x    = alloc((size_t)1024*512*4);
  size_t o_whT  = alloc((size_t)GATE*1024*4);
  size_t o_whmT = alloc((size_t)1024*32*4);
  size_t o_A    = alloc((size_t)1024*GATE*4);
  size_t o_H0   = alloc((size_t)1024*1024*4);
  size_t o_H1   = alloc((size_t)1024*1024*4);
  size_t o_H2   = alloc((size_t)1024*1024*4);
  size_t o_lp   = alloc((size_t)1024*5*8);
  size_t o_latf = alloc((size_t)1024*5120*4);
  size_t o_lath = alloc((size_t)5120*1024*2);
  size_t o_latl = alloc((size_t)5120*1024*2);
  size_t o_Z    = alloc((size_t)5120*8);
  size_t o_cand = alloc((size_t)1024*66*4);
  size_t o_nll  = alloc((size_t)1024*4);
  size_t base   = off;

  const size_t woimg = (size_t)250*32*8192;
  auto need = [&](int ch, int pre){
    return base + (pre ? 2*((woimg + 255) & ~(size_t)255) : 0)
                + (((size_t)ch*250*2*4 + 255) & ~(size_t)255)
                + (((size_t)ch*VOC*4 + 255) & ~(size_t)255);
  };
  int PRE, CH;
  if      (need(1280,1) <= ws_size){ PRE=1; CH=1280; }
  else if (need(640, 1) <= ws_size){ PRE=1; CH=640;  }
  else if (need(1280,0) <= ws_size){ PRE=0; CH=1280; }
  else                              { PRE=0; CH=640;  }
  size_t o_wohi = 0, o_wolo = 0;
  if (PRE){ o_wohi = alloc(woimg); o_wolo = alloc(woimg); }
  size_t o_part = alloc((size_t)CH*250*2*4);
  size_t o_s    = alloc((size_t)CH*VOC*4);
  (void)o_s;

  float*  hbuf  = (float*) (ws + o_hbuf);
  int*    bars  = (int*)   (ws + o_bars);
  int*    mfl   = (int*)   (ws + o_mfl);
  float*  tfti  = (float*) (ws + o_tfti);
  float*  xbuf  = (float*) (ws + o_x);
  float*  whT   = (float*) (ws + o_whT);
  float*  whmT  = (float*) (ws + o_whmT);
  float*  Abuf  = (float*) (ws + o_A);
  float*  H0    = (float*) (ws + o_H0);
  float*  H1    = (float*) (ws + o_H1);
  float*  H2    = (float*) (ws + o_H2);
  double* lpbuf = (double*)(ws + o_lp);
  float*  latf  = (float*) (ws + o_latf);
  ushort* lath  = (ushort*)(ws + o_lath);
  ushort* latl  = (ushort*)(ws + o_latl);
  double* Zbuf  = (double*)(ws + o_Z);
  int*    candb = (int*)   (ws + o_cand);
  float*  nllb  = (float*) (ws + o_nll);
  char*   wohi  = ws + o_wohi;
  char*   wolo  = ws + o_wolo;
  float*  partb = (float*) (ws + o_part);
  float*  Sbuf  = (float*) (ws + o_s);

  int perl = NWG*16 + 16;
  int* flags0 = bars;             int* gen0 = flags0 + NWG*16;
  int* flags1 = bars + perl;      int* gen1 = flags1 + NWG*16;
  int* flags2 = bars + 2*perl;    int* gen2 = flags2 + NWG*16;
  int* mfl0 = mfl;  int* mfl1 = mfl + 8*16;  int* mfl2 = mfl + 16*16;

  hipMemsetAsync(d_ws, 0, zero_bytes, stream);
  embed_kernel<<<1024, 128, 0, stream>>>(ys, emb, xbuf);
  if (PRE)
    wosplit_kernel<<<dim3(32,250), 256, 0, stream>>>(Wo, (uint32_t*)wohi, (uint32_t*)wolo);

  // layer 0
  gemm_f32_kernel<0><<<dim3(33,8), 256, 0, stream>>>(xbuf, Wx0, b0, Abuf, nullptr, nullptr, 512, GATE);
  whT_kernel<<<dim3(129,32), dim3(32,8), 0, stream>>>(Wh0, whT);
  whmT_kernel<<<128, 256, 0, stream>>>(Wh0, whmT);
  scan_kernel<<<NWG, 512, 0, stream>>>(Abuf, whT, whmT, hbuf, H0, nullptr, nullptr,
                                       flags0, gen0, mfl0, tfti);
  // layer 1 (emits cf/df)
  gemm_f32_kernel<0><<<dim3(33,8), 256, 0, stream>>>(H0, Wx1, b1, Abuf, nullptr, nullptr, 1024, GATE);
  whT_kernel<<<dim3(129,32), dim3(32,8), 0, stream>>>(Wh1, whT);
  whmT_kernel<<<128, 256, 0, stream>>>(Wh1, whmT);
  hipMemsetAsync(hbuf, 0, 2*8192*4, stream);
  scan_kernel<<<NWG, 512, 0, stream>>>(Abuf, whT, whmT, hbuf, H1, out + 1025, out + 1,
                                       flags1, gen1, mfl1, tfti);
  // layer 2
  gemm_f32_kernel<0><<<dim3(33,8), 256, 0, stream>>>(H1, Wx2, b2, Abuf, nullptr, nullptr, 1024, GATE);
  whT_kernel<<<dim3(129,32), dim3(32,8), 0, stream>>>(Wh2, whT);
  whmT_kernel<<<128, 256, 0, stream>>>(Wh2, whmT);
  hipMemsetAsync(hbuf, 0, 2*8192*4, stream);
  scan_kernel<<<NWG, 512, 0, stream>>>(Abuf, whT, whmT, hbuf, H2, nullptr, nullptr,
                                       flags2, gen2, mfl2, tfti);

  prior_kernel<<<1024, 64, 0, stream>>>(H2, Wp, bp, lpbuf);
  gemm_f32_kernel<2><<<dim3(40,8), 256, 0, stream>>>(H2, Wl, bl, latf, lath, latl, 1024, 5120);

  int nchunks = 5120 / CH;
  for (int c = 0; c < nchunks; c++){
    if (PRE)
      wo_gemm_kernel<1><<<dim3(250, CH/128), 256, 0, stream>>>(lath, latl, Wo, bo, wohi, wolo, Sbuf, partb, c*CH);
    else
      wo_gemm_kernel<0><<<dim3(250, CH/128), 256, 0, stream>>>(lath, latl, Wo, bo, nullptr, nullptr, Sbuf, partb, c*CH);
    cand_kernel<<<CH/5, 256, 0, stream>>>(Sbuf, lpbuf, partb, Zbuf + c*CH, candb, c*(CH/5));
  }
  refine_kernel<<<1024, 256, 0, stream>>>(latf, Wo, bo, lpbuf, Zbuf, candb, ys, nllb, out + 17409);
  loss_kernel<<<1, 64, 0, stream>>>(nllb, ys, out);
}

// Round 14
// 8617.554 us; speedup vs baseline: 1.4671x; 1.0404x over previous
//
#include <hip/hip_runtime.h>
#include <stdint.h>
#include <stddef.h>

#define TT   128
#define GATE 4128
#define VOC  32000
#define NWG  256

typedef float  f32x4 __attribute__((ext_vector_type(4)));
typedef short  bf16x8 __attribute__((ext_vector_type(8)));
typedef unsigned short u16x4 __attribute__((ext_vector_type(4)));

__device__ __forceinline__ float bf2f(ushort u){
  union { uint32_t i; float f; } c; c.i = ((uint32_t)u) << 16; return c.f;
}
__device__ __forceinline__ ushort f2bf(float x){
  uint32_t u = __builtin_bit_cast(uint32_t, x);
  uint32_t r = (u + 0x7fffu + ((u >> 16) & 1u)) >> 16;
  return (ushort)r;
}

// ---------------------------------------------------------------- embed
__global__ void embed_kernel(const int* __restrict__ ys, const float* __restrict__ emb,
                             float* __restrict__ x){
  int r = blockIdx.x;
  int t = r >> 3, b = r & 7;
  int tok = ys[b*129 + t];
  f32x4 v = *(const f32x4*)&emb[(size_t)tok*512 + threadIdx.x*4];
  *(f32x4*)&x[(size_t)r*512 + threadIdx.x*4] = v;
}

// ---------------------------------------------------------------- full Wh transpose
__global__ void whT_kernel(const float* __restrict__ Wh, float* __restrict__ WhT){
  __shared__ float tile[32][33];
  int g0 = blockIdx.x*32, k0 = blockIdx.y*32;
  int tx = threadIdx.x, ty = threadIdx.y;
  for (int i = ty; i < 32; i += 8)
    tile[i][tx] = Wh[(size_t)(k0+i)*GATE + g0 + tx];
  __syncthreads();
  for (int i = ty; i < 32; i += 8)
    WhT[(size_t)(g0+i)*1024 + k0 + tx] = tile[tx][i];
}

// ---------------------------------------------------------------- WhmT[k][c]
__global__ void whmT_kernel(const float* __restrict__ Wh, float* __restrict__ WhmT){
  int idx = blockIdx.x*256 + threadIdx.x;
  int k = idx >> 5, c = idx & 31;
  WhmT[idx] = Wh[(size_t)k*GATE + 4096 + c];
}

// ---------------------------------------------------------------- generic W -> pre-swizzled split-bf16 images
// W[K][N] -> blocks (nt, ks): 8KB image == LDS byte image for rdfrag. grid (KS, NT).
__global__ __launch_bounds__(256) void wsplit_kernel(const float* __restrict__ W,
                                                     uint32_t* __restrict__ hi_img,
                                                     uint32_t* __restrict__ lo_img,
                                                     int K, int N, int KS){
  __shared__ float tile[32][132];
  int ks = blockIdx.x, nt = blockIdx.y;
  int tid = threadIdx.x;
  for (int i = tid; i < 4096; i += 256){
    int n = nt*128 + (i & 127);
    int k = ks*32 + (i >> 7);
    tile[i>>7][i&127] = (n < N) ? W[(size_t)k*N + n] : 0.f;
  }
  __syncthreads();
  size_t base = ((size_t)(nt*KS + ks)) << 11;   // *2048 u32
  for (int i = tid; i < 2048; i += 256){
    int p = i*4;
    int row = p >> 6, kgpos = (p >> 4) & 3, sub = (p >> 2) & 3;
    int kg = kgpos ^ ((row >> 1) & 3);
    int ke = kg*8 + 2*sub;
    float x0 = tile[ke][row], x1 = tile[ke+1][row];
    ushort h0 = f2bf(x0), h1 = f2bf(x1);
    ushort l0 = f2bf(x0 - bf2f(h0)), l1 = f2bf(x1 - bf2f(h1));
    hi_img[base + i] = (uint32_t)h0 | ((uint32_t)h1 << 16);
    lo_img[base + i] = (uint32_t)l0 | ((uint32_t)l1 << 16);
  }
}

// ---------------------------------------------------------------- Wo -> pre-swizzled images (r11, kept)
__global__ __launch_bounds__(256) void wosplit_kernel(const float* __restrict__ Wo,
                                                      uint32_t* __restrict__ hi_img,
                                                      uint32_t* __restrict__ lo_img){
  __shared__ float tile[32][132];
  int ks = blockIdx.x, nt = blockIdx.y;
  int tid = threadIdx.x;
  for (int i = tid; i < 4096; i += 256)
    tile[i>>7][i&127] = Wo[(size_t)(ks*32 + (i>>7))*VOC + nt*128 + (i&127)];
  __syncthreads();
  size_t base = ((size_t)(nt*32 + ks)) << 11;
  for (int i = tid; i < 2048; i += 256){
    int p = i*4;
    int row = p >> 6, kgpos = (p >> 4) & 3, sub = (p >> 2) & 3;
    int kg = kgpos ^ ((row >> 1) & 3);
    int ke = kg*8 + 2*sub;
    float x0 = tile[ke][row], x1 = tile[ke+1][row];
    ushort h0 = f2bf(x0), h1 = f2bf(x1);
    ushort l0 = f2bf(x0 - bf2f(h0)), l1 = f2bf(x1 - bf2f(h1));
    hi_img[base + i] = (uint32_t)h0 | ((uint32_t)h1 << 16);
    lo_img[base + i] = (uint32_t)l0 | ((uint32_t)l1 << 16);
  }
}

// ---------------------------------------------------------------- X -> bf16 hi/lo split (elementwise)
__global__ __launch_bounds__(256) void xsplit_kernel(const float* __restrict__ X,
                                                     ushort* __restrict__ hi, ushort* __restrict__ lo){
  int i = (blockIdx.x*256 + threadIdx.x)*4;
  f32x4 v = *(const f32x4*)&X[i];
  u16x4 h, l;
  #pragma unroll
  for (int j = 0; j < 4; j++){
    ushort hb = f2bf(v[j]);
    h[j] = hb;
    l[j] = f2bf(v[j] - bf2f(hb));
  }
  *(u16x4*)&hi[i] = h;
  *(u16x4*)&lo[i] = l;
}

// ---------------------------------------------------------------- f32 GEMM fallback (MODE 0: +b ; MODE 2: tanh + split)
template<int MODE>
__global__ __launch_bounds__(256) void gemm_f32_kernel(
    const float* __restrict__ X, const float* __restrict__ W, const float* __restrict__ bias,
    float* __restrict__ O1, ushort* __restrict__ O2, ushort* __restrict__ O3,
    int Kdim, int N)
{
  __shared__ float At[2][8][132];
  __shared__ float Bs[2][8][132];
  int tid = threadIdx.x;
  int n0 = blockIdx.x*128, r0 = blockIdx.y*128;
  int tx = tid & 15, ty = tid >> 4;
  int am = tid >> 1, akq = tid & 1;
  int bk = tid >> 5, bnc = tid & 31;
  float acc[8][8];
  #pragma unroll
  for (int i=0;i<8;i++)
    #pragma unroll
    for (int j=0;j<8;j++) acc[i][j]=0.f;
  {
    f32x4 av = *(const f32x4*)&X[(size_t)(r0+am)*Kdim + akq*4];
    At[0][akq*4+0][am]=av.x; At[0][akq*4+1][am]=av.y; At[0][akq*4+2][am]=av.z; At[0][akq*4+3][am]=av.w;
    int nb = n0 + bnc*4;
    f32x4 bv = {0.f,0.f,0.f,0.f};
    if (nb + 3 < N) bv = *(const f32x4*)&W[(size_t)bk*N + nb];
    *(f32x4*)&Bs[0][bk][bnc*4] = bv;
  }
  __syncthreads();
  int nk = Kdim >> 3;
  for (int ksb = 0; ksb < nk; ksb++){
    int cb = ksb & 1;
    if (ksb + 1 < nk){
      int k0 = (ksb+1)*8, bs = cb^1;
      f32x4 av = *(const f32x4*)&X[(size_t)(r0+am)*Kdim + k0 + akq*4];
      At[bs][akq*4+0][am]=av.x; At[bs][akq*4+1][am]=av.y; At[bs][akq*4+2][am]=av.z; At[bs][akq*4+3][am]=av.w;
      int nb = n0 + bnc*4;
      f32x4 bv = {0.f,0.f,0.f,0.f};
      if (nb + 3 < N) bv = *(const f32x4*)&W[(size_t)(k0+bk)*N + nb];
      *(f32x4*)&Bs[bs][bk][bnc*4] = bv;
    }
    #pragma unroll
    for (int k = 0; k < 8; k++){
      float a[8], b[8];
      *(f32x4*)&a[0] = *(const f32x4*)&At[cb][k][ty*8];
      *(f32x4*)&a[4] = *(const f32x4*)&At[cb][k][ty*8+4];
      *(f32x4*)&b[0] = *(const f32x4*)&Bs[cb][k][tx*8];
      *(f32x4*)&b[4] = *(const f32x4*)&Bs[cb][k][tx*8+4];
      #pragma unroll
      for (int i=0;i<8;i++)
        #pragma unroll
        for (int j=0;j<8;j++) acc[i][j] = fmaf(a[i], b[j], acc[i][j]);
    }
    __syncthreads();
  }
  #pragma unroll
  for (int i=0;i<8;i++){
    int r = r0 + ty*8 + i;
    #pragma unroll
    for (int j=0;j<8;j+=4){
      int n = n0 + tx*8 + j;
      if (n + 3 < N){
        f32x4 v;
        v.x = acc[i][j+0] + bias[n+0];
        v.y = acc[i][j+1] + bias[n+1];
        v.z = acc[i][j+2] + bias[n+2];
        v.w = acc[i][j+3] + bias[n+3];
        if (MODE >= 1){
          v.x = tanhf(v.x); v.y = tanhf(v.y); v.z = tanhf(v.z); v.w = tanhf(v.w);
        }
        *(f32x4*)&O1[(size_t)r*N + n] = v;
        if (MODE == 2){
          u16x4 h, l;
          #pragma unroll
          for (int q = 0; q < 4; q++){
            ushort hb = f2bf(v[q]);
            h[q] = hb;
            l[q] = f2bf(v[q] - bf2f(hb));
          }
          *(u16x4*)&O2[(size_t)r*N + n] = h;
          *(u16x4*)&O3[(size_t)r*N + n] = l;
        }
      }
    }
  }
}

// ---------------------------------------------------------------- shared MFMA helpers
__device__ __forceinline__ void stageA_ldsK(const ushort* gsrc, char* ldsbase, int row0, int k0,
                                            int tid, int Kdim){
  int lane = tid & 63, wv = tid >> 6;
  #pragma unroll
  for (int s = 0; s < 2; s++){
    int p = wv*1024 + s*4096 + lane*16;
    int row = p >> 6;
    int kg  = (p >> 4) & 3;
    int kgs = kg ^ ((row >> 1) & 3);
    const ushort* ga = gsrc + (size_t)(row0 + row)*Kdim + k0 + kgs*8;
    __builtin_amdgcn_global_load_lds(
        (const __attribute__((address_space(1))) void*)ga,
        (__attribute__((address_space(3))) void*)(ldsbase + wv*1024 + s*4096),
        16, 0, 0);
  }
}
__device__ __forceinline__ void stageB_img(const char* img, char* lds, int nt, int ks, int KS, int tid){
  int lane = tid & 63, wv = tid >> 6;
  const char* base = img + (((size_t)(nt*KS + ks)) << 13);
  #pragma unroll
  for (int s = 0; s < 2; s++){
    int p = wv*1024 + s*4096 + lane*16;
    __builtin_amdgcn_global_load_lds(
        (const __attribute__((address_space(1))) void*)(base + p),
        (__attribute__((address_space(3))) void*)(lds + p),
        16, 0, 0);
  }
}
__device__ __forceinline__ bf16x8 rdfrag(const char* base, int row, int kg){
  int byte = row*64 + ((kg ^ ((row >> 1) & 3)) << 4);
  return *(const bf16x8*)(base + byte);
}

// ---------------------------------------------------------------- generic split-bf16 MFMA GEMM: O = X@W + b
// MODE 0: O1 f32 ; MODE 2: t=tanh(.), O1=t f32, O2/O3 = bf16 hi/lo
template<int MODE>
__global__ __launch_bounds__(256) void xw_gemm_kernel(
    const ushort* __restrict__ Xhi, const ushort* __restrict__ Xlo, int Kdim, int KS,
    const char* __restrict__ whi_img, const char* __restrict__ wlo_img,
    const float* __restrict__ bias, int N,
    float* __restrict__ O1, ushort* __restrict__ O2, ushort* __restrict__ O3)
{
  __shared__ __align__(16) char smem[66560];
  __shared__ float bo_s[128];
  int tid = threadIdx.x;
  int nt = blockIdx.x, mt = blockIdx.y;
  int n0 = nt*128, row0 = mt*128;
  if (tid < 128) bo_s[tid] = (n0 + tid < N) ? bias[n0 + tid] : 0.f;
  f32x4 acc[4][4] = {};

  stageA_ldsK(Xhi, smem + 0,    row0, 0, tid, Kdim);
  stageA_ldsK(Xlo, smem + 8192, row0, 0, tid, Kdim);
  stageB_img(whi_img, smem + 16384, nt, 0, KS, tid);
  stageB_img(wlo_img, smem + 24576, nt, 0, KS, tid);
  __syncthreads();

  int lane = tid & 63, wv = tid >> 6;
  int wr = wv >> 1, wc = wv & 1;
  int rl = lane & 15, kgl = lane >> 4;
  for (int ks = 0; ks < KS; ks++){
    char* cb = smem + (ks & 1)*32768;
    if (ks + 1 < KS){
      char* nb2 = smem + ((ks+1) & 1)*32768;
      stageA_ldsK(Xhi, nb2,        row0, (ks+1)*32, tid, Kdim);
      stageA_ldsK(Xlo, nb2 + 8192, row0, (ks+1)*32, tid, Kdim);
      stageB_img(whi_img, nb2 + 16384, nt, ks+1, KS, tid);
      stageB_img(wlo_img, nb2 + 24576, nt, ks+1, KS, tid);
    }
    bf16x8 ah[4], al[4], bh[4], bl2[4];
    #pragma unroll
    for (int m = 0; m < 4; m++){
      int row = wr*64 + m*16 + rl;
      ah[m] = rdfrag(cb,        row, kgl);
      al[m] = rdfrag(cb + 8192, row, kgl);
    }
    #pragma unroll
    for (int n = 0; n < 4; n++){
      int rw = wc*64 + n*16 + rl;
      bh[n]  = rdfrag(cb + 16384, rw, kgl);
      bl2[n] = rdfrag(cb + 24576, rw, kgl);
    }
    #pragma unroll
    for (int m = 0; m < 4; m++)
      #pragma unroll
      for (int n = 0; n < 4; n++){
        acc[m][n] = __builtin_amdgcn_mfma_f32_16x16x32_bf16(ah[m], bh[n],  acc[m][n], 0,0,0);
        acc[m][n] = __builtin_amdgcn_mfma_f32_16x16x32_bf16(ah[m], bl2[n], acc[m][n], 0,0,0);
        acc[m][n] = __builtin_amdgcn_mfma_f32_16x16x32_bf16(al[m], bh[n],  acc[m][n], 0,0,0);
      }
    __syncthreads();
  }

  float* st = (float*)smem;
  #pragma unroll
  for (int m = 0; m < 4; m++){
    int rb = wr*64 + m*16 + (lane >> 4)*4;
    #pragma unroll
    for (int n = 0; n < 4; n++){
      int col = wc*64 + n*16 + rl;
      #pragma unroll
      for (int j = 0; j < 4; j++)
        st[(rb + j)*130 + col] = acc[m][n][j];
    }
  }
  __syncthreads();
  int row = tid >> 1, half = tid & 1;
  int r = row0 + row;
  for (int jc = 0; jc < 64; jc += 4){
    int n = n0 + half*64 + jc;
    if (n + 3 < N){
      f32x4 v;
      #pragma unroll
      for (int j = 0; j < 4; j++){
        float x = st[row*130 + half*64 + jc + j] + bo_s[half*64 + jc + j];
        if (MODE == 2) x = tanhf(x);
        v[j] = x;
      }
      *(f32x4*)&O1[(size_t)r*N + n] = v;
      if (MODE == 2){
        u16x4 h, l;
        #pragma unroll
        for (int q = 0; q < 4; q++){
          ushort hb = f2bf(v[q]);
          h[q] = hb;
          l[q] = f2bf(v[q] - bf2f(hb));
        }
        *(u16x4*)&O2[(size_t)r*N + n] = h;
        *(u16x4*)&O3[(size_t)r*N + n] = l;
      }
    }
  }
}

// ---------------------------------------------------------------- distributed-flag grid barrier (r11-proven)
__device__ __forceinline__ void gbar(int* flags, int* gen, int ep, int wg, int tid){
  if (wg == 0){
    if (tid == 0){
      __threadfence();
      __hip_atomic_store(&flags[0], ep, __ATOMIC_RELAXED, __HIP_MEMORY_SCOPE_AGENT);
    }
    if (tid < NWG){
      while (__hip_atomic_load(&flags[tid*16], __ATOMIC_RELAXED, __HIP_MEMORY_SCOPE_AGENT) < ep)
        __builtin_amdgcn_s_sleep(1);
    }
    __syncthreads();
    if (tid == 0){
      __threadfence();
      __hip_atomic_store(gen, ep, __ATOMIC_RELAXED, __HIP_MEMORY_SCOPE_AGENT);
      __threadfence();
    }
  } else {
    if (tid == 0){
      __threadfence();
      __hip_atomic_store(&flags[wg*16], ep, __ATOMIC_RELAXED, __HIP_MEMORY_SCOPE_AGENT);
      while (__hip_atomic_load(gen, __ATOMIC_RELAXED, __HIP_MEMORY_SCOPE_AGENT) < ep)
        __builtin_amdgcn_s_sleep(2);
      __threadfence();
    }
  }
}

// ---------------------------------------------------------------- ON-LSTM scan (r11/r13 exact)
__global__ __launch_bounds__(512) void scan_kernel(
    const float* __restrict__ A,
    const float* __restrict__ WhT,
    const float* __restrict__ WhmT,
    float* __restrict__ hbuf,
    float* __restrict__ H,
    float* __restrict__ cf_out, float* __restrict__ df_out,
    int* bar_flags, int* bar_gen, int* mflags, float* tfti)
{
  __shared__ __align__(16) float wls[1024*20];
  __shared__ __align__(16) float hls[1024*12];
  __shared__ __align__(16) float gpw[2][2][32][36];
  __shared__ float projg[8][16];
  __shared__ float cst[8][4];
  __shared__ float mpart[8][8][4];
  __shared__ float projmb[32];

  int tid = threadIdx.x, wg = blockIdx.x;
  int e0 = wg*4, chunk = wg >> 4;

  #pragma unroll
  for (int c = 0; c < 16; c++){
    int gcol = (c>>2)*1024 + e0 + (c&3);
    const float* src = WhT + (size_t)gcol*1024;
    for (int k = tid; k < 1024; k += 512)
      wls[k*20 + c] = src[k];
  }
  if (tid < 32) cst[tid & 7][tid >> 3] = 0.f;
  __syncthreads();

  int cq = tid >> 8;
  int bh = (tid >> 7) & 1;
  int kp = tid & 127;
  bool isM = (wg < 8);
  int mcg = tid & 7, mkp = tid >> 3;

  for (int t = 0; t < TT; t++){
    int rb = (t+1) & 1, wb = t & 1;
    float Ag = 0.f;
    if (tid < 128){
      int c = tid >> 3, b = tid & 7;
      Ag = A[(size_t)(t*8+b)*GATE + (c>>2)*1024 + e0 + (c&3)];
    }
    float Am = 0.f;
    if (isM && tid < 32) Am = A[(size_t)(t*8+wg)*GATE + 4096 + tid];

    {
      const f32x4* hb4 = (const f32x4*)&hbuf[rb*8192];
      #pragma unroll
      for (int s2 = 0; s2 < 4; s2++){
        int i4 = s2*512 + tid;
        f32x4 v = hb4[i4];
        int k = i4 >> 1, h2 = i4 & 1;
        *(f32x4*)&hls[k*12 + h2*4] = v;
      }
    }
    __syncthreads();

    if (isM){
      float macc[4] = {0.f,0.f,0.f,0.f};
      #pragma unroll
      for (int j = 0; j < 16; j++){
        int k = j*64 + mkp;
        f32x4 wm = *(const f32x4*)&WhmT[k*32 + mcg*4];
        float hv = hls[k*12 + wg];
        macc[0] += wm.x*hv; macc[1] += wm.y*hv; macc[2] += wm.z*hv; macc[3] += wm.w*hv;
      }
      #pragma unroll
      for (int off = 8; off < 64; off <<= 1){
        macc[0] += __shfl_xor(macc[0], off);
        macc[1] += __shfl_xor(macc[1], off);
        macc[2] += __shfl_xor(macc[2], off);
        macc[3] += __shfl_xor(macc[3], off);
      }
      if ((tid & 63) < 8){
        int wv = tid >> 6;
        mpart[wv][mcg][0] = macc[0]; mpart[wv][mcg][1] = macc[1];
        mpart[wv][mcg][2] = macc[2]; mpart[wv][mcg][3] = macc[3];
      }
      __syncthreads();
      if (tid < 32){
        float s = Am;
        #pragma unroll
        for (int wv = 0; wv < 8; wv++) s += mpart[wv][tid>>2][tid&3];
        projmb[tid] = s;
      }
      __syncthreads();
      if (tid < 32){
        int half = tid >> 4, j = tid & 15;
        float x = projmb[tid];
        float mx = x;
        #pragma unroll
        for (int o = 1; o < 16; o <<= 1) mx = fmaxf(mx, __shfl_xor(mx, o));
        float e = expf(x - mx);
        float ssum = e;
        #pragma unroll
        for (int o = 1; o < 16; o <<= 1) ssum += __shfl_xor(ssum, o);
        float sm = e / ssum;
        float c = sm;
        #pragma unroll
        for (int o = 1; o < 16; o <<= 1){
          float t2 = __shfl_up(c, o);
          if (j >= o) c += t2;
        }
        float outv = half ? (1.f - c) : c;
        tfti[half*128 + wg*16 + j] = outv;
        if (cf_out != nullptr && half == 0){
          cf_out[(wg*TT + t)*16 + j] = c;
          float ts = c;
          #pragma unroll
          for (int o = 1; o < 16; o <<= 1) ts += __shfl_xor(ts, o);
          if (j == 0) df_out[wg*TT + t] = 16.f - ts;
        }
      }
      __syncthreads();
      if (tid == 0){
        __threadfence();
        __hip_atomic_store(&mflags[wg*16], t+1, __ATOMIC_RELAXED, __HIP_MEMORY_SCOPE_AGENT);
      }
    }

    float acc[8][4];
    #pragma unroll
    for (int c = 0; c < 8; c++)
      #pragma unroll
      for (int b2 = 0; b2 < 4; b2++) acc[c][b2] = 0.f;
    #pragma unroll
    for (int j = 0; j < 8; j++){
      int k = j*128 + kp;
      float wa[8], hb[4];
      *(f32x4*)&wa[0] = *(const f32x4*)&wls[k*20 + cq*8];
      *(f32x4*)&wa[4] = *(const f32x4*)&wls[k*20 + cq*8 + 4];
      *(f32x4*)&hb[0] = *(const f32x4*)&hls[k*12 + bh*4];
      #pragma unroll
      for (int c = 0; c < 8; c++)
        #pragma unroll
        for (int b2 = 0; b2 < 4; b2++)
          acc[c][b2] = fmaf(wa[c], hb[b2], acc[c][b2]);
    }
    #pragma unroll
    for (int c = 0; c < 8; c++)
      #pragma unroll
      for (int b2 = 0; b2 < 4; b2++){
        float v = acc[c][b2];
        v += __shfl_xor(v, 1);
        v += __shfl_xor(v, 2);
        acc[c][b2] = v;
      }
    if ((kp & 3) == 0){
      int kg = kp >> 2;
      #pragma unroll
      for (int c = 0; c < 8; c++){
        f32x4 v4 = { acc[c][0], acc[c][1], acc[c][2], acc[c][3] };
        *(f32x4*)&gpw[cq][bh][kg][c*4] = v4;
      }
    }
    __syncthreads();
    if (tid < 128){
      int c = tid >> 3, b = tid & 7;
      float s = Ag;
      #pragma unroll
      for (int g = 0; g < 32; g++) s += gpw[c>>3][b>>2][g][(c&7)*4 + (b&3)];
      projg[b][c] = s;
    }
    if (tid < 8){
      while (__hip_atomic_load(&mflags[tid*16], __ATOMIC_RELAXED, __HIP_MEMORY_SCOPE_AGENT) < t+1)
        __builtin_amdgcn_s_sleep(1);
    }
    __syncthreads();
    if (tid < 32){
      int b = tid & 7, e = tid >> 3;
      float gi = projg[b][e], gf = projg[b][4+e], go = projg[b][8+e], gg = projg[b][12+e];
      float iv = 1.f/(1.f+expf(-gi)), fv = 1.f/(1.f+expf(-gf)), ov = 1.f/(1.f+expf(-go));
      float gv = tanhf(gg);
      float tf = __hip_atomic_load(&tfti[b*16 + chunk],       __ATOMIC_RELAXED, __HIP_MEMORY_SCOPE_AGENT);
      float ti = __hip_atomic_load(&tfti[128 + b*16 + chunk], __ATOMIC_RELAXED, __HIP_MEMORY_SCOPE_AGENT);
      float w  = tf*ti;
      float c2 = (fv*w + (tf - w))*cst[b][e] + (iv*w + (ti - w))*gv;
      cst[b][e] = c2;
      float h2 = ov * tanhf(c2);
      hbuf[wb*8192 + (e0+e)*8 + b] = h2;
      H[(size_t)(t*8+b)*1024 + e0 + e] = h2;
    }
    __syncthreads();
    gbar(bar_flags, bar_gen, t+1, wg, tid);
    __syncthreads();
  }
}

// ---------------------------------------------------------------- wo_gemm (r11, unchanged)
__device__ __forceinline__ void stageB_cv(const float* __restrict__ Wo, int n0, int k0, int tid,
                                          char* bhi, char* blo){
  int kp = tid & 15, g = tid >> 4;
  const float* src = Wo + (size_t)(k0 + 2*kp)*VOC + n0 + g*8;
  f32x4 v00 = *(const f32x4*)(src);
  f32x4 v01 = *(const f32x4*)(src + 4);
  f32x4 v10 = *(const f32x4*)(src + VOC);
  f32x4 v11 = *(const f32x4*)(src + VOC + 4);
  int kg = kp >> 2, sub = kp & 3;
  #pragma unroll
  for (int j = 0; j < 8; j++){
    float x0 = (j < 4) ? v00[j] : v01[j-4];
    float x1 = (j < 4) ? v10[j] : v11[j-4];
    ushort h0 = f2bf(x0), h1 = f2bf(x1);
    ushort l0 = f2bf(x0 - bf2f(h0)), l1 = f2bf(x1 - bf2f(h1));
    int n = g*8 + j;
    int byte = n*64 + ((kg ^ ((n >> 1) & 3)) << 4) + sub*4;
    *(uint32_t*)(bhi + byte) = (uint32_t)h0 | ((uint32_t)h1 << 16);
    *(uint32_t*)(blo + byte) = (uint32_t)l0 | ((uint32_t)l1 << 16);
  }
}

template<int PRE>
__global__ __launch_bounds__(256) void wo_gemm_kernel(
    const ushort* __restrict__ Ahi, const ushort* __restrict__ Alo,
    const float* __restrict__ Wo, const float* __restrict__ bo,
    const char* __restrict__ wohi_img, const char* __restrict__ wolo_img,
    float* __restrict__ S, float* __restrict__ partials, int rowbase)
{
  __shared__ __align__(16) char smem[66560];
  __shared__ float bo_s[128];
  __shared__ float redm[128][2], reds[128][2];
  int tid = threadIdx.x;
  int nt = blockIdx.x, mt = blockIdx.y;
  int n0 = nt*128, row0loc = mt*128, row0 = rowbase + row0loc;
  if (tid < 128) bo_s[tid] = bo[n0 + tid];
  f32x4 acc[4][4] = {};

  stageA_ldsK(Ahi, smem + 0,    row0, 0, tid, 1024);
  stageA_ldsK(Alo, smem + 8192, row0, 0, tid, 1024);
  if (PRE){
    stageB_img(wohi_img, smem + 16384, nt, 0, 32, tid);
    stageB_img(wolo_img, smem + 24576, nt, 0, 32, tid);
  } else {
    stageB_cv(Wo, n0, 0, tid, smem + 16384, smem + 24576);
  }
  __syncthreads();

  int lane = tid & 63, wv = tid >> 6;
  int wr = wv >> 1, wc = wv & 1;
  int rl = lane & 15, kgl = lane >> 4;
  for (int ks = 0; ks < 32; ks++){
    char* cb = smem + (ks & 1)*32768;
    if (ks + 1 < 32){
      char* nb2 = smem + ((ks+1) & 1)*32768;
      stageA_ldsK(Ahi, nb2,        row0, (ks+1)*32, tid, 1024);
      stageA_ldsK(Alo, nb2 + 8192, row0, (ks+1)*32, tid, 1024);
      if (PRE){
        stageB_img(wohi_img, nb2 + 16384, nt, ks+1, 32, tid);
        stageB_img(wolo_img, nb2 + 24576, nt, ks+1, 32, tid);
      } else {
        stageB_cv(Wo, n0, (ks+1)*32, tid, nb2 + 16384, nb2 + 24576);
      }
    }
    bf16x8 ah[4], al[4], bh[4], bl2[4];
    #pragma unroll
    for (int m = 0; m < 4; m++){
      int row = wr*64 + m*16 + rl;
      ah[m] = rdfrag(cb,        row, kgl);
      al[m] = rdfrag(cb + 8192, row, kgl);
    }
    #pragma unroll
    for (int n = 0; n < 4; n++){
      int rw = wc*64 + n*16 + rl;
      bh[n]  = rdfrag(cb + 16384, rw, kgl);
      bl2[n] = rdfrag(cb + 24576, rw, kgl);
    }
    #pragma unroll
    for (int m = 0; m < 4; m++)
      #pragma unroll
      for (int n = 0; n < 4; n++){
        acc[m][n] = __builtin_amdgcn_mfma_f32_16x16x32_bf16(ah[m], bh[n],  acc[m][n], 0,0,0);
        acc[m][n] = __builtin_amdgcn_mfma_f32_16x16x32_bf16(ah[m], bl2[n], acc[m][n], 0,0,0);
        acc[m][n] = __builtin_amdgcn_mfma_f32_16x16x32_bf16(al[m], bh[n],  acc[m][n], 0,0,0);
      }
    __syncthreads();
  }

  float* st = (float*)smem;
  #pragma unroll
  for (int m = 0; m < 4; m++){
    int rb = wr*64 + m*16 + (lane >> 4)*4;
    #pragma unroll
    for (int n = 0; n < 4; n++){
      int col = wc*64 + n*16 + rl;
      #pragma unroll
      for (int j = 0; j < 4; j++)
        st[(rb + j)*130 + col] = acc[m][n][j];
    }
  }
  __syncthreads();
  int row = tid >> 1, half = tid & 1;
  float lmax = -1e30f;
  for (int jc = 0; jc < 64; jc += 4){
    f32x4 v;
    #pragma unroll
    for (int j = 0; j < 4; j++){
      float x = st[row*130 + half*64 + jc + j] + bo_s[half*64 + jc + j];
      st[row*130 + half*64 + jc + j] = x;
      v[j] = x;
      lmax = fmaxf(lmax, x);
    }
    *(f32x4*)&S[(size_t)(row0loc + row)*VOC + n0 + half*64 + jc] = v;
  }
  redm[row][half] = lmax;
  __syncthreads();
  float rm = fmaxf(redm[row][0], redm[row][1]);
  float lsum = 0.f;
  for (int jc = 0; jc < 64; jc++)
    lsum += expf(st[row*130 + half*64 + jc] - rm);
  reds[row][half] = lsum;
  __syncthreads();
  if (half == 0){
    float2 pr; pr.x = rm; pr.y = reds[row][0] + reds[row][1];
    *(float2*)&partials[((size_t)(row0loc + row)*250 + nt)*2] = pr;
  }
}

// ---------------------------------------------------------------- candidates (+fused Z finalize)
__device__ __forceinline__ float cand_q(const float* __restrict__ srow, int v,
                                        float l0, float l1, float l2, float l3, float l4){
  float t0 = l0 + srow[v];
  float t1 = l1 + srow[VOC   + v];
  float t2 = l2 + srow[2*VOC + v];
  float t3 = l3 + srow[3*VOC + v];
  float t4 = l4 + srow[4*VOC + v];
  float m = fmaxf(fmaxf(fmaxf(t0,t1),fmaxf(t2,t3)),t4);
  return m + logf(expf(t0-m)+expf(t1-m)+expf(t2-m)+expf(t3-m)+expf(t4-m));
}
__global__ __launch_bounds__(256) void cand_kernel(
    const float* __restrict__ S, const double* __restrict__ lp,
    const float* __restrict__ partials, double* __restrict__ Zd,
    int* __restrict__ cand, int rbase)
{
  int g = blockIdx.x; int r = rbase + g; int tid = threadIdx.x;
  __shared__ float lpk[5];
  __shared__ double zk[5];
  __shared__ float rq[256]; __shared__ int rv[256];
  __shared__ double rd[256];
  __shared__ int cnt; __shared__ int list[64];
  if (tid == 0) cnt = 0;
  for (int k = 0; k < 5; k++){
    size_t lrow = (size_t)(g*5 + k);
    float m = -1e30f;
    for (int t2 = tid; t2 < 250; t2 += 256) m = fmaxf(m, partials[(lrow*250 + t2)*2]);
    rq[tid] = m; __syncthreads();
    for (int s = 128; s; s >>= 1){ if (tid < s) rq[tid] = fmaxf(rq[tid], rq[tid+s]); __syncthreads(); }
    float M = rq[0]; __syncthreads();
    double ssum = 0.0;
    for (int t2 = tid; t2 < 250; t2 += 256){
      float pm = partials[(lrow*250 + t2)*2];
      float se = partials[(lrow*250 + t2)*2 + 1];
      ssum += exp((double)pm - (double)M)*(double)se;
    }
    rd[tid] = ssum; __syncthreads();
    for (int s = 128; s; s >>= 1){ if (tid < s) rd[tid] += rd[tid+s]; __syncthreads(); }
    if (tid == 0){
      double z = (double)M + log(rd[0]);
      zk[k] = z;
      Zd[lrow] = z;
    }
    __syncthreads();
  }
  if (tid < 5) lpk[tid] = (float)(lp[r*5 + tid] - zk[tid]);
  __syncthreads();
  float l0 = lpk[0], l1 = lpk[1], l2 = lpk[2], l3 = lpk[3], l4 = lpk[4];
  const float* srow = S + (size_t)(g*5)*VOC;
  float bq = -1e30f; int bv = 0;
  for (int v = tid; v < VOC; v += 256){
    float q = cand_q(srow, v, l0,l1,l2,l3,l4);
    if (q > bq){ bq = q; bv = v; }
  }
  rq[tid] = bq; rv[tid] = bv; __syncthreads();
  for (int s = 128; s > 0; s >>= 1){
    if (tid < s){
      if (rq[tid+s] > rq[tid] || (rq[tid+s] == rq[tid] && rv[tid+s] < rv[tid])){
        rq[tid] = rq[tid+s]; rv[tid] = rv[tid+s];
      }
    }
    __syncthreads();
  }
  float M = rq[0]; int argv = rv[0];
  for (int v = tid; v < VOC; v += 256){
    float q = cand_q(srow, v, l0,l1,l2,l3,l4);
    if (q >= M - 0.02f && v != argv){
      int ix = atomicAdd(&cnt, 1);
      if (ix < 63) list[ix] = v;
    }
  }
  __syncthreads();
  int nc = cnt < 63 ? cnt : 63;
  if (tid == 0){ cand[r*66] = nc + 1; cand[r*66 + 1] = argv; }
  if (tid < nc) cand[r*66 + 2 + tid] = list[tid];
}

// ---------------------------------------------------------------- exact f64 refinement: pred + gold nll
__global__ __launch_bounds__(256) void refine_kernel(
    const float* __restrict__ lat, const float* __restrict__ Wo, const float* __restrict__ bo,
    const double* __restrict__ lp, const double* __restrict__ Z,
    const int* __restrict__ cand, const int* __restrict__ ys,
    float* __restrict__ nll, float* __restrict__ pred_out)
{
  int r = blockIdx.x, tid = threadIdx.x;
  int b = r & 7, l = r >> 3;
  int nc = cand[r*66];
  if (nc < 0) nc = 0;
  if (nc > 64) nc = 64;
  __shared__ double dred[5][4];
  __shared__ double bestval; __shared__ int bestv;
  if (tid == 0){ bestval = -1e300; bestv = 0; }
  __syncthreads();
  int gold = ys[b*129 + l + 1];
  for (int ci = 0; ci <= nc; ci++){
    int v = (ci < nc) ? cand[r*66 + 1 + ci] : gold;
    double p0=0,p1=0,p2=0,p3=0,p4=0;
    for (int h = tid; h < 1024; h += 256){
      double w = (double)Wo[(size_t)h*VOC + v];
      p0 += (double)lat[((size_t)r*5+0)*1024 + h]*w;
      p1 += (double)lat[((size_t)r*5+1)*1024 + h]*w;
      p2 += (double)lat[((size_t)r*5+2)*1024 + h]*w;
      p3 += (double)lat[((size_t)r*5+3)*1024 + h]*w;
      p4 += (double)lat[((size_t)r*5+4)*1024 + h]*w;
    }
    #pragma unroll
    for (int off = 32; off; off >>= 1){
      p0 += __shfl_down(p0, off); p1 += __shfl_down(p1, off);
      p2 += __shfl_down(p2, off); p3 += __shfl_down(p3, off);
      p4 += __shfl_down(p4, off);
    }
    if ((tid & 63) == 0){
      int w = tid >> 6;
      dred[0][w]=p0; dred[1][w]=p1; dred[2][w]=p2; dred[3][w]=p3; dred[4][w]=p4;
    }
    __syncthreads();
    if (tid == 0){
      double bv = (double)bo[v];
      double tk[5]; double mx = -1e300;
      #pragma unroll
      for (int k = 0; k < 5; k++){
        double sk = dred[k][0]+dred[k][1]+dred[k][2]+dred[k][3] + bv;
        tk[k] = (lp[r*5+k] - Z[r*5+k]) + sk;
        mx = tk[k] > mx ? tk[k] : mx;
      }
      double q = mx + log(exp(tk[0]-mx)+exp(tk[1]-mx)+exp(tk[2]-mx)+exp(tk[3]-mx)+exp(tk[4]-mx));
      if (ci < nc){
        if (q > bestval || (q == bestval && v < bestv)){ bestval = q; bestv = v; }
      } else {
        nll[r] = (float)(-q);
      }
    }
    __syncthreads();
  }
  if (tid == 0) pred_out[b*TT + l] = (float)bestv;
}

// ---------------------------------------------------------------- prior
__global__ __launch_bounds__(64) void prior_kernel(
    const float* __restrict__ H2, const float* __restrict__ Wp, const float* __restrict__ bp,
    double* __restrict__ lp)
{
  int r = blockIdx.x, tid = threadIdx.x;
  double p0=0,p1=0,p2=0,p3=0,p4=0;
  for (int h = tid; h < 1024; h += 64){
    double x = (double)H2[(size_t)r*1024 + h];
    const float* w = &Wp[h*5];
    p0 += x*(double)w[0]; p1 += x*(double)w[1]; p2 += x*(double)w[2];
    p3 += x*(double)w[3]; p4 += x*(double)w[4];
  }
  #pragma unroll
  for (int off = 32; off; off >>= 1){
    p0 += __shfl_down(p0, off); p1 += __shfl_down(p1, off);
    p2 += __shfl_down(p2, off); p3 += __shfl_down(p3, off);
    p4 += __shfl_down(p4, off);
  }
  if (tid == 0){
    double lg[5] = { p0+(double)bp[0], p1+(double)bp[1], p2+(double)bp[2], p3+(double)bp[3], p4+(double)bp[4] };
    double mx = lg[0];
    #pragma unroll
    for (int k = 1; k < 5; k++) mx = lg[k] > mx ? lg[k] : mx;
    double s = 0;
    #pragma unroll
    for (int k = 0; k < 5; k++) s += exp(lg[k]-mx);
    double lse = mx + log(s);
    #pragma unroll
    for (int k = 0; k < 5; k++) lp[r*5+k] = lg[k] - lse;
  }
}

// ---------------------------------------------------------------- loss
__global__ void loss_kernel(const float* __restrict__ nll, const int* __restrict__ ys,
                            float* __restrict__ out){
  int tid = threadIdx.x;
  __shared__ float ps[8];
  if (tid < 8){
    float s = 0.f, ms = 0.f;
    for (int l = 0; l < TT; l++){
      int gold = ys[tid*129 + l + 1];
      float m = (gold != 0) ? 1.f : 0.f;
      s  += nll[l*8 + tid]*m;
      ms += m;
    }
    ps[tid] = s/(ms + 1e-13f);
  }
  __syncthreads();
  if (tid == 0){
    float t = 0.f;
    for (int b = 0; b < 8; b++) t += ps[b];
    out[0] = t/8.f;
  }
}

// ================================================================ launcher
extern "C" void kernel_launch(void* const* d_in, const int* in_sizes, int n_in,
                              void* d_out, int out_size, void* d_ws, size_t ws_size,
                              hipStream_t stream)
{
  (void)in_sizes; (void)n_in; (void)out_size;
  const int*   ys  = (const int*)  d_in[0];
  const float* emb = (const float*)d_in[1];
  const float* Wx0 = (const float*)d_in[2];
  const float* Wh0 = (const float*)d_in[3];
  const float* b0  = (const float*)d_in[4];
  const float* Wx1 = (const float*)d_in[5];
  const float* Wh1 = (const float*)d_in[6];
  const float* b1  = (const float*)d_in[7];
  const float* Wx2 = (const float*)d_in[8];
  const float* Wh2 = (const float*)d_in[9];
  const float* b2  = (const float*)d_in[10];
  const float* Wp  = (const float*)d_in[11];
  const float* bp  = (const float*)d_in[12];
  const float* Wl  = (const float*)d_in[13];
  const float* bl  = (const float*)d_in[14];
  const float* Wo  = (const float*)d_in[15];
  const float* bo  = (const float*)d_in[16];
  float* out = (float*)d_out;

  char* ws = (char*)d_ws;
  size_t off = 0;
  auto alloc = [&](size_t bytes){ size_t o = off; off += (bytes + 255) & ~(size_t)255; return o; };
  size_t o_hbuf = alloc(2*8192*4);
  size_t o_bars = alloc(3*(NWG*16 + 16)*sizeof(int));
  size_t o_mfl  = alloc(3*8*16*sizeof(int));
  size_t zero_bytes = off;
  size_t o_tfti = alloc(256*4);
  size_t o_x    = alloc((size_t)1024*512*4);
  size_t o_whT  = alloc((size_t)GATE*1024*4);
  size_t o_whmT = alloc((size_t)1024*32*4);
  size_t o_A    = alloc((size_t)1024*GATE*4);
  size_t o_H0   = alloc((size_t)1024*1024*4);
  size_t o_H1   = alloc((size_t)1024*1024*4);
  size_t o_H2   = alloc((size_t)1024*1024*4);
  size_t o_lp   = alloc((size_t)1024*5*8);
  size_t o_latf = alloc((size_t)1024*5120*4);
  size_t o_lath = alloc((size_t)5120*1024*2);
  size_t o_latl = alloc((size_t)5120*1024*2);
  size_t o_Z    = alloc((size_t)5120*8);
  size_t o_cand = alloc((size_t)1024*66*4);
  size_t o_nll  = alloc((size_t)1024*4);
  size_t base   = off;

  const size_t woimg  = (size_t)250*32*8192;                    // 65.5 MB each
  const size_t wx0img = (size_t)33*16*8192;                     // 4.3 MB each
  const size_t wx1img = (size_t)33*32*8192;                     // 8.65 MB each
  const size_t wlimg  = (size_t)40*32*8192;                     // 10.5 MB each
  const size_t xsz    = (size_t)1024*1024*2;                    // 2 MB each
  const size_t imgtot = 2*(wx0img + 2*wx1img + wlimg + xsz) + 6*256;
  auto need = [&](int ch, int pre, int img){
    return base + (pre ? 2*((woimg + 255) & ~(size_t)255) : 0)
                + (img ? imgtot + 4096 : 0)
                + (((size_t)ch*250*2*4 + 255) & ~(size_t)255)
                + (((size_t)ch*VOC*4 + 255) & ~(size_t)255);
  };
  int PRE, CH, IMG;
  if      (need(1280,1,1) <= ws_size){ PRE=1; CH=1280; IMG=1; }
  else if (need(1280,1,0) <= ws_size){ PRE=1; CH=1280; IMG=0; }
  else if (need(640, 1,0) <= ws_size){ PRE=1; CH=640;  IMG=0; }
  else if (need(1280,0,0) <= ws_size){ PRE=0; CH=1280; IMG=0; }
  else                                { PRE=0; CH=640;  IMG=0; }
  size_t o_wohi = 0, o_wolo = 0;
  if (PRE){ o_wohi = alloc(woimg); o_wolo = alloc(woimg); }
  size_t o_wx0h=0,o_wx0l=0,o_wx1h=0,o_wx1l=0,o_wx2h=0,o_wx2l=0,o_wlh=0,o_wll=0,o_xh=0,o_xl=0;
  if (IMG){
    o_wx0h = alloc(wx0img); o_wx0l = alloc(wx0img);
    o_wx1h = alloc(wx1img); o_wx1l = alloc(wx1img);
    o_wx2h = alloc(wx1img); o_wx2l = alloc(wx1img);
    o_wlh  = alloc(wlimg);  o_wll  = alloc(wlimg);
    o_xh   = alloc(xsz);    o_xl   = alloc(xsz);
  }
  size_t o_part = alloc((size_t)CH*250*2*4);
  size_t o_s    = alloc((size_t)CH*VOC*4);
  (void)o_s;

  float*  hbuf  = (float*) (ws + o_hbuf);
  int*    bars  = (int*)   (ws + o_bars);
  int*    mfl   = (int*)   (ws + o_mfl);
  float*  tfti  = (float*) (ws + o_tfti);
  float*  xbuf  = (float*) (ws + o_x);
  float*  whT   = (float*) (ws + o_whT);
  float*  whmT  = (float*) (ws + o_whmT);
  float*  Abuf  = (float*) (ws + o_A);
  float*  H0    = (float*) (ws + o_H0);
  float*  H1    = (float*) (ws + o_H1);
  float*  H2    = (float*) (ws + o_H2);
  double* lpbuf = (double*)(ws + o_lp);
  float*  latf  = (float*) (ws + o_latf);
  ushort* lath  = (ushort*)(ws + o_lath);
  ushort* latl  = (ushort*)(ws + o_latl);
  double* Zbuf  = (double*)(ws + o_Z);
  int*    candb = (int*)   (ws + o_cand);
  float*  nllb  = (float*) (ws + o_nll);
  char*   wohi  = ws + o_wohi;
  char*   wolo  = ws + o_wolo;
  float*  partb = (float*) (ws + o_part);
  float*  Sbuf  = (float*) (ws + o_s);
  ushort* xhi   = (ushort*)(ws + o_xh);
  ushort* xlo   = (ushort*)(ws + o_xl);

  int perl = NWG*16 + 16;
  int* flags0 = bars;             int* gen0 = flags0 + NWG*16;
  int* flags1 = bars + perl;      int* gen1 = flags1 + NWG*16;
  int* flags2 = bars + 2*perl;    int* gen2 = flags2 + NWG*16;
  int* mfl0 = mfl;  int* mfl1 = mfl + 8*16;  int* mfl2 = mfl + 16*16;

  hipMemsetAsync(d_ws, 0, zero_bytes, stream);
  embed_kernel<<<1024, 128, 0, stream>>>(ys, emb, xbuf);
  if (PRE)
    wosplit_kernel<<<dim3(32,250), 256, 0, stream>>>(Wo, (uint32_t*)wohi, (uint32_t*)wolo);
  if (IMG){
    wsplit_kernel<<<dim3(16,33), 256, 0, stream>>>(Wx0, (uint32_t*)(ws+o_wx0h), (uint32_t*)(ws+o_wx0l), 512, GATE, 16);
    wsplit_kernel<<<dim3(32,33), 256, 0, stream>>>(Wx1, (uint32_t*)(ws+o_wx1h), (uint32_t*)(ws+o_wx1l), 1024, GATE, 32);
    wsplit_kernel<<<dim3(32,33), 256, 0, stream>>>(Wx2, (uint32_t*)(ws+o_wx2h), (uint32_t*)(ws+o_wx2l), 1024, GATE, 32);
    wsplit_kernel<<<dim3(32,40), 256, 0, stream>>>(Wl,  (uint32_t*)(ws+o_wlh),  (uint32_t*)(ws+o_wll),  1024, 5120, 32);
  }

  // layer 0
  if (IMG){
    xsplit_kernel<<<512, 256, 0, stream>>>(xbuf, xhi, xlo);   // 1024*512 elems
    xw_gemm_kernel<0><<<dim3(33,8), 256, 0, stream>>>(xhi, xlo, 512, 16,
        ws+o_wx0h, ws+o_wx0l, b0, GATE, Abuf, nullptr, nullptr);
  } else {
    gemm_f32_kernel<0><<<dim3(33,8), 256, 0, stream>>>(xbuf, Wx0, b0, Abuf, nullptr, nullptr, 512, GATE);
  }
  whT_kernel<<<dim3(129,32), dim3(32,8), 0, stream>>>(Wh0, whT);
  whmT_kernel<<<128, 256, 0, stream>>>(Wh0, whmT);
  scan_kernel<<<NWG, 512, 0, stream>>>(Abuf, whT, whmT, hbuf, H0, nullptr, nullptr,
                                       flags0, gen0, mfl0, tfti);
  // layer 1 (emits cf/df)
  if (IMG){
    xsplit_kernel<<<1024, 256, 0, stream>>>(H0, xhi, xlo);
    xw_gemm_kernel<0><<<dim3(33,8), 256, 0, stream>>>(xhi, xlo, 1024, 32,
        ws+o_wx1h, ws+o_wx1l, b1, GATE, Abuf, nullptr, nullptr);
  } else {
    gemm_f32_kernel<0><<<dim3(33,8), 256, 0, stream>>>(H0, Wx1, b1, Abuf, nullptr, nullptr, 1024, GATE);
  }
  whT_kernel<<<dim3(129,32), dim3(32,8), 0, stream>>>(Wh1, whT);
  whmT_kernel<<<128, 256, 0, stream>>>(Wh1, whmT);
  hipMemsetAsync(hbuf, 0, 2*8192*4, stream);
  scan_kernel<<<NWG, 512, 0, stream>>>(Abuf, whT, whmT, hbuf, H1, out + 1025, out + 1,
                                       flags1, gen1, mfl1, tfti);
  // layer 2
  if (IMG){
    xsplit_kernel<<<1024, 256, 0, stream>>>(H1, xhi, xlo);
    xw_gemm_kernel<0><<<dim3(33,8), 256, 0, stream>>>(xhi, xlo, 1024, 32,
        ws+o_wx2h, ws+o_wx2l, b2, GATE, Abuf, nullptr, nullptr);
  } else {
    gemm_f32_kernel<0><<<dim3(33,8), 256, 0, stream>>>(H1, Wx2, b2, Abuf, nullptr, nullptr, 1024, GATE);
  }
  whT_kernel<<<dim3(129,32), dim3(32,8), 0, stream>>>(Wh2, whT);
  whmT_kernel<<<128, 256, 0, stream>>>(Wh2, whmT);
  hipMemsetAsync(hbuf, 0, 2*8192*4, stream);
  scan_kernel<<<NWG, 512, 0, stream>>>(Abuf, whT, whmT, hbuf, H2, nullptr, nullptr,
                                       flags2, gen2, mfl2, tfti);

  prior_kernel<<<1024, 64, 0, stream>>>(H2, Wp, bp, lpbuf);
  if (IMG){
    xsplit_kernel<<<1024, 256, 0, stream>>>(H2, xhi, xlo);
    xw_gemm_kernel<2><<<dim3(40,8), 256, 0, stream>>>(xhi, xlo, 1024, 32,
        ws+o_wlh, ws+o_wll, bl, 5120, latf, lath, latl);
  } else {
    gemm_f32_kernel<2><<<dim3(40,8), 256, 0, stream>>>(H2, Wl, bl, latf, lath, latl, 1024, 5120);
  }

  int nchunks = 5120 / CH;
  for (int c = 0; c < nchunks; c++){
    if (PRE)
      wo_gemm_kernel<1><<<dim3(250, CH/128), 256, 0, stream>>>(lath, latl, Wo, bo, wohi, wolo, Sbuf, partb, c*CH);
    else
      wo_gemm_kernel<0><<<dim3(250, CH/128), 256, 0, stream>>>(lath, latl, Wo, bo, nullptr, nullptr, Sbuf, partb, c*CH);
    cand_kernel<<<CH/5, 256, 0, stream>>>(Sbuf, lpbuf, partb, Zbuf + c*CH, candb, c*(CH/5));
  }
  refine_kernel<<<1024, 256, 0, stream>>>(latf, Wo, bo, lpbuf, Zbuf, candb, ys, nllb, out + 17409);
  loss_kernel<<<1, 64, 0, stream>>>(nllb, ys, out);
}